// Round 14
// baseline (1843.578 us; speedup 1.0000x reference)
//
#include <hip/hip_runtime.h>
#include <hip/hip_bf16.h>
#include <hip/hip_fp16.h>
#include <stdint.h>

typedef unsigned int u32;
typedef unsigned short u16;
typedef __attribute__((ext_vector_type(8))) short short8;
typedef __attribute__((ext_vector_type(4))) float f32x4;
typedef _Float16 half2v __attribute__((ext_vector_type(2)));

#if defined(__has_builtin)
#if __has_builtin(__builtin_amdgcn_fdot2)
#define HAVE_FDOT2 1
#endif
#endif

// ---------- helpers ----------
__device__ __forceinline__ float bf2f_u(u32 lo16) { return __uint_as_float(lo16 << 16); }
__device__ __forceinline__ u32 f2bf_bits(float x) {
  u32 u = __float_as_uint(x);
  return (u + 0x7fffu + ((u >> 16) & 1u)) >> 16;
}
__device__ __forceinline__ u32 pk2bf_tr(float x, float y) {  // truncating pack, 2 VALU
  return (__float_as_uint(y) & 0xffff0000u) | (__float_as_uint(x) >> 16);
}
__device__ __forceinline__ u32 pkh(float x, float y) {  // two f16 in a u32
  return (u32)__half_as_ushort(__float2half(x)) |
         ((u32)__half_as_ushort(__float2half(y)) << 16);
}
__device__ __forceinline__ float dot2h(u32 w, u32 h, float acc) {
#ifdef HAVE_FDOT2
  return __builtin_amdgcn_fdot2(__builtin_bit_cast(half2v, w), __builtin_bit_cast(half2v, h),
                                acc, false);
#else
  union { u32 u; __half2 h2; } uw, uh;
  uw.u = w; uh.u = h;
  float2 wf = __half22float2(uw.h2);
  float2 hf = __half22float2(uh.h2);
  return acc + wf.x * hf.x + wf.y * hf.y;
#endif
}
__device__ __forceinline__ float sigf(float x) { return 1.0f / (1.0f + __expf(-x)); }
__device__ __forceinline__ float tanhf_fast(float x) {
  float ax = fabsf(x);
  float e = __expf(-2.0f * ax);
  float t = (1.0f - e) / (1.0f + e);
  return x < 0.0f ? -t : t;
}
__device__ __forceinline__ float eluf(float x) { return x > 0.0f ? x : __expf(x) - 1.0f; }
__device__ __forceinline__ float lreluf(float x) { return x > 0.0f ? x : 0.2f * x; }

__device__ __forceinline__ int maskmode(const void* am) { return (*(const u32*)am) > 0xFFu; }
__device__ __forceinline__ int ldmask(const void* p, int i, int mb) {
  return mb ? (int)((const unsigned char*)p)[i] : ((const int*)p)[i];
}

__global__ void k_marker(float* out) { out[0] = 12345.0f; }

// ---------- K0: precompute W_gat @ a_l / a_r (wave-per-output, coalesced) ----------
__global__ __launch_bounds__(256) void k_prep(const float* __restrict__ Wgat,
                                              const float* __restrict__ al,
                                              const float* __restrict__ ar,
                                              float* __restrict__ alproj,
                                              float* __restrict__ arproj) {
  int w = blockIdx.x * 4 + (threadIdx.x >> 6);
  int lane = threadIdx.x & 63;
  if (w >= 3840) return;
  int mk = w / 320, d = w % 320;
  const float* wrow = Wgat + ((size_t)mk * 320 + d) * 256;
  const float* alp = al + mk * 256;
  const float* arp = ar + mk * 256;
  float sa = 0.f, sb = 0.f;
#pragma unroll
  for (int q = 0; q < 4; ++q) {
    int o = lane + q * 64;
    float wv = wrow[o];
    sa += wv * alp[o];
    sb += wv * arp[o];
  }
#pragma unroll
  for (int off = 32; off; off >>= 1) {
    sa += __shfl_down(sa, off, 64);
    sb += __shfl_down(sb, off, 64);
  }
  if (lane == 0) { alproj[w] = sa; arproj[w] = sb; }
}

// ---------- K0b: Whh_c -> wt4[k4][800] uint4 of f16 pairs ----------
__global__ void k_pack(const float* __restrict__ whhc, uint4* __restrict__ wt4) {
  int idx = blockIdx.x * 256 + threadIdx.x;
  if (idx >= 20000) return;
  int k4 = idx / 800, r = idx % 800;
  const float* p = whhc + r * 200 + k4 * 8;
  wt4[idx] = (uint4){pkh(p[0], p[1]), pkh(p[2], p[3]), pkh(p[4], p[5]), pkh(p[6], p[7])};
}

// ---------- K1: input GEMM (MFMA bf16), BK=64 (24 barriers vs 48), plain Z[m][640] ----------
__global__ __launch_bounds__(256) void k_gemm_in(
    const float* __restrict__ emb, const float* __restrict__ Wf, const float* __restrict__ Wb,
    const float* __restrict__ biasf, const float* __restrict__ biasb, float* __restrict__ Z) {
  __shared__ u16 Albs[128 * 72];  // 64 k + 8 pad (pitch 72 u16 -> 2-way bank alias, free)
  __shared__ u16 Blbs[128 * 72];
  __shared__ float bias_l[128];
  const int tid = threadIdx.x;
  const int n0 = blockIdx.x * 128;
  const int m0 = blockIdx.y * 128;

  if (tid < 128) {
    int ng = n0 + tid;
    bias_l[tid] = (ng < 320) ? biasf[ng] : biasb[ng - 320];
  }
  const int srow = tid >> 1, shalf = tid & 1;
  const float* asrc = emb + (size_t)(m0 + srow) * 768 + shalf * 32;
  const int ngb = n0 + srow;
  const float* bsrc =
      ((ngb < 320) ? (Wf + (size_t)ngb * 768) : (Wb + (size_t)(ngb - 320) * 768)) + shalf * 32;
  u32* aw = (u32*)&Albs[srow * 72 + shalf * 32];
  u32* bw = (u32*)&Blbs[srow * 72 + shalf * 32];

  const int lane = tid & 63;
  const int lr = lane & 15, sub = lane >> 4;
  const int wv = tid >> 6, wm = wv >> 1, wn = wv & 1;
  const u16* abase = &Albs[(wm * 64 + lr) * 72 + sub * 8];
  const u16* bbase = &Blbs[(wn * 64 + lr) * 72 + sub * 8];

  f32x4 acc[4][4];
#pragma unroll
  for (int i = 0; i < 4; ++i)
#pragma unroll
    for (int j = 0; j < 4; ++j) acc[i][j] = (f32x4)(0.f);

  float4 av[8], bv[8];
  u32 pra[16], prb[16];
#pragma unroll
  for (int q = 0; q < 8; ++q) {
    av[q] = *(const float4*)(asrc + q * 4);
    bv[q] = *(const float4*)(bsrc + q * 4);
  }
#pragma unroll
  for (int q = 0; q < 8; ++q) {
    pra[2 * q] = pk2bf_tr(av[q].x, av[q].y);
    pra[2 * q + 1] = pk2bf_tr(av[q].z, av[q].w);
    prb[2 * q] = pk2bf_tr(bv[q].x, bv[q].y);
    prb[2 * q + 1] = pk2bf_tr(bv[q].z, bv[q].w);
  }

  for (int it = 0; it < 12; ++it) {
    __syncthreads();
#pragma unroll
    for (int q = 0; q < 16; ++q) { aw[q] = pra[q]; bw[q] = prb[q]; }
    __syncthreads();
    const bool more = (it + 1 < 12);
    if (more) {
      const int k0 = (it + 1) * 64;
#pragma unroll
      for (int q = 0; q < 8; ++q) {
        av[q] = *(const float4*)(asrc + k0 + q * 4);
        bv[q] = *(const float4*)(bsrc + k0 + q * 4);
      }
    }
#pragma unroll
    for (int ks = 0; ks < 2; ++ks) {
      short8 bfr[4];
#pragma unroll
      for (int nf = 0; nf < 4; ++nf) bfr[nf] = *(const short8*)(bbase + nf * 1152 + ks * 32);
#pragma unroll
      for (int mf = 0; mf < 4; ++mf) {
        short8 af = *(const short8*)(abase + mf * 1152 + ks * 32);
#pragma unroll
        for (int nf = 0; nf < 4; ++nf)
          acc[mf][nf] = __builtin_amdgcn_mfma_f32_16x16x32_bf16(af, bfr[nf], acc[mf][nf], 0, 0, 0);
      }
    }
    if (more) {
#pragma unroll
      for (int q = 0; q < 8; ++q) {
        pra[2 * q] = pk2bf_tr(av[q].x, av[q].y);
        pra[2 * q + 1] = pk2bf_tr(av[q].z, av[q].w);
        prb[2 * q] = pk2bf_tr(bv[q].x, bv[q].y);
        prb[2 * q + 1] = pk2bf_tr(bv[q].z, bv[q].w);
      }
    }
  }
#pragma unroll
  for (int mf = 0; mf < 4; ++mf) {
#pragma unroll
    for (int nf = 0; nf < 4; ++nf) {
      int col = wn * 64 + nf * 16 + lr;
      float bias = bias_l[col];
      size_t mrow = (size_t)m0 + wm * 64 + mf * 16 + sub * 4;
#pragma unroll
      for (int j = 0; j < 4; ++j)
        Z[(mrow + j) * 640 + n0 + col] = acc[mf][nf][j] + bias;
    }
  }
}

// ---------- K2: token LSTM (round-12 exact: best measured 682us) ----------
__global__ __launch_bounds__(320, 1) void k_lstm_tok(const float* __restrict__ Z,
                                                     const float* __restrict__ Whhf,
                                                     const float* __restrict__ Whhb,
                                                     float* __restrict__ hf,
                                                     float* __restrict__ hb) {
  __shared__ uint2 wq[20 * 320];
  __shared__ alignas(16) u32 hpk[40];
  __shared__ float zbuf[320];
  const int tid = threadIdx.x;
  const int c = blockIdx.x >> 1;
  const int dir = blockIdx.x & 1;
  const float* Whh = dir ? Whhb : Whhf;
  float* hout = dir ? hb : hf;

  for (int idx = tid; idx < 20 * 320; idx += 320) {
    int k4 = idx / 320, r = idx % 320;
    const float* p = Whh + (size_t)r * 80 + k4 * 4;
    wq[idx] = (uint2){pkh(p[0], p[1]), pkh(p[2], p[3])};
  }
  if (tid < 40) hpk[tid] = 0;
  __syncthreads();

  const int j = tid;
  const uint2* wcol = wq + j;
  uint2 wv0 = wcol[0], wv1 = wcol[320], wv2 = wcol[640], wv3 = wcol[960];
  uint2 wv4 = wcol[1280], wv5 = wcol[1600], wv6 = wcol[1920], wv7 = wcol[2240];
  uint2 wv8 = wcol[2560], wv9 = wcol[2880], wv10 = wcol[3200], wv11 = wcol[3520];
  uint2 wv12 = wcol[3840], wv13 = wcol[4160], wv14 = wcol[4480], wv15 = wcol[4800];
  uint2 wv16 = wcol[5120], wv17 = wcol[5440], wv18 = wcol[5760], wv19 = wcol[6080];

  const int sgn = dir ? -1 : 1;
  const int t0 = dir ? 1023 : 0;
  const float* zb = Z + (size_t)c * 1024 * 640 + dir * 320 + j;
  float zc = zb[(size_t)t0 * 640];
  float zn = zb[(size_t)(t0 + sgn) * 640];
  float cst = 0.f;

  for (int t = 0; t < 1024; ++t) {
    const int tt = t0 + sgn * t;
    float zp = 0.f;
    if (t + 2 < 1024) zp = zb[(size_t)(t0 + sgn * (t + 2)) * 640];
    float a0 = zc, a1 = 0.f, a2 = 0.f, a3 = 0.f;
    {
      uint4 h0 = *(const uint4*)&hpk[0];
      a0 = dot2h(wv0.x, h0.x, a0); a1 = dot2h(wv0.y, h0.y, a1);
      a2 = dot2h(wv1.x, h0.z, a2); a3 = dot2h(wv1.y, h0.w, a3);
      uint4 h1 = *(const uint4*)&hpk[4];
      a0 = dot2h(wv2.x, h1.x, a0); a1 = dot2h(wv2.y, h1.y, a1);
      a2 = dot2h(wv3.x, h1.z, a2); a3 = dot2h(wv3.y, h1.w, a3);
      uint4 h2 = *(const uint4*)&hpk[8];
      a0 = dot2h(wv4.x, h2.x, a0); a1 = dot2h(wv4.y, h2.y, a1);
      a2 = dot2h(wv5.x, h2.z, a2); a3 = dot2h(wv5.y, h2.w, a3);
      uint4 h3 = *(const uint4*)&hpk[12];
      a0 = dot2h(wv6.x, h3.x, a0); a1 = dot2h(wv6.y, h3.y, a1);
      a2 = dot2h(wv7.x, h3.z, a2); a3 = dot2h(wv7.y, h3.w, a3);
      uint4 h4 = *(const uint4*)&hpk[16];
      a0 = dot2h(wv8.x, h4.x, a0); a1 = dot2h(wv8.y, h4.y, a1);
      a2 = dot2h(wv9.x, h4.z, a2); a3 = dot2h(wv9.y, h4.w, a3);
      uint4 h5 = *(const uint4*)&hpk[20];
      a0 = dot2h(wv10.x, h5.x, a0); a1 = dot2h(wv10.y, h5.y, a1);
      a2 = dot2h(wv11.x, h5.z, a2); a3 = dot2h(wv11.y, h5.w, a3);
      uint4 h6 = *(const uint4*)&hpk[24];
      a0 = dot2h(wv12.x, h6.x, a0); a1 = dot2h(wv12.y, h6.y, a1);
      a2 = dot2h(wv13.x, h6.z, a2); a3 = dot2h(wv13.y, h6.w, a3);
      uint4 h7 = *(const uint4*)&hpk[28];
      a0 = dot2h(wv14.x, h7.x, a0); a1 = dot2h(wv14.y, h7.y, a1);
      a2 = dot2h(wv15.x, h7.z, a2); a3 = dot2h(wv15.y, h7.w, a3);
      uint4 h8 = *(const uint4*)&hpk[32];
      a0 = dot2h(wv16.x, h8.x, a0); a1 = dot2h(wv16.y, h8.y, a1);
      a2 = dot2h(wv17.x, h8.z, a2); a3 = dot2h(wv17.y, h8.w, a3);
      uint4 h9 = *(const uint4*)&hpk[36];
      a0 = dot2h(wv18.x, h9.x, a0); a1 = dot2h(wv18.y, h9.y, a1);
      a2 = dot2h(wv19.x, h9.z, a2); a3 = dot2h(wv19.y, h9.w, a3);
    }
    zbuf[j] = (a0 + a1) + (a2 + a3);
    __syncthreads();
    if (j < 80) {
      float iv = sigf(zbuf[j]);
      float fv = sigf(zbuf[80 + j]);
      float gv = tanhf_fast(zbuf[160 + j]);
      float ov = sigf(zbuf[240 + j]);
      cst = fv * cst + iv * gv;
      float h = ov * tanhf_fast(cst);
      ((u16*)hpk)[j] = (u16)__half_as_ushort(__float2half(h));
      hout[((size_t)c * 1024 + tt) * 80 + j] = h;
    }
    zc = zn; zn = zp;
    __syncthreads();
  }
}

// ---------- span representation ----------
__device__ __forceinline__ float span_val(const float* __restrict__ hf,
                                          const float* __restrict__ hb, int c, int i, int j,
                                          int d) {
  size_t base = (size_t)c * 1024 * 80;
  if (d < 80) return hf[base + (size_t)j * 80 + d] - hf[base + (size_t)(i - 1) * 80 + d];
  if (d < 160) return hb[base + (size_t)i * 80 + (d - 80)] - hb[base + (size_t)(j + 1) * 80 + (d - 80)];
  if (d < 240) return hf[base + (size_t)(i - 1) * 80 + (d - 160)];
  return hb[base + (size_t)(j + 1) * 80 + (d - 240)];
}

__global__ __launch_bounds__(256) void k_span(const float* __restrict__ hf,
                                              const float* __restrict__ hb,
                                              const int* __restrict__ cspan,
                                              const int* __restrict__ aspan,
                                              const void* __restrict__ amask,
                                              float* __restrict__ adus, float* __restrict__ cembo) {
  const int c = blockIdx.x, tid = threadIdx.x;
  const int mb = maskmode(amask);
  int ci = cspan[c * 2], cj = cspan[c * 2 + 1];
  for (int d = tid; d < 320; d += 256) cembo[c * 320 + d] = span_val(hf, hb, c, ci, cj, d);
  for (int idx = tid; idx < 32 * 320; idx += 256) {
    int a = idx / 320, d = idx % 320;
    float v = 0.f;
    if (ldmask(amask, c * 32 + a, mb)) {
      int ai = aspan[(c * 32 + a) * 2], aj = aspan[(c * 32 + a) * 2 + 1];
      v = span_val(hf, hb, c, ai, aj, d);
    }
    adus[(size_t)c * 10240 + idx] = v;
  }
}

// ---------- K3a: GAT per (comment, metapath); Wst tile prefetch ----------
__global__ __launch_bounds__(256) void k_gat(
    const float* __restrict__ adus_ws, const float* __restrict__ alproj,
    const float* __restrict__ arproj, const float* __restrict__ Wgat,
    const float* __restrict__ bgat, const int* __restrict__ isrc, const int* __restrict__ idst,
    const int* __restrict__ irel, const void* __restrict__ imask, const int* __restrict__ tsrc,
    const int* __restrict__ tdst, const int* __restrict__ trel, const void* __restrict__ tmask,
    const void* __restrict__ amdet, float* __restrict__ zgat) {
  __shared__ float adus_l[32][321];
  __shared__ float Wst[16][64];
  __shared__ float hp_t[32][66];
  __shared__ float sl_l[96], sr_l[96];
  __shared__ float e_l[144], alpha_l[144], mx_l[96], den_l[96];
  __shared__ int src_l[48], dst_l[48], valid_l[48];
  const int c = blockIdx.x >> 2, m = blockIdx.x & 3;
  const int tid = threadIdx.x;
  const int mb = maskmode(amdet);

  if (tid < 48) {
    int e = tid, s, d, r, mk;
    if (m < 2) {
      s = isrc[c * 48 + e]; d = idst[c * 48 + e]; r = irel[c * 48 + e];
      mk = ldmask(imask, c * 48 + e, mb);
    } else {
      s = tdst[c * 48 + e]; d = tsrc[c * 48 + e]; r = trel[c * 48 + e];
      mk = ldmask(tmask, c * 48 + e, mb);
    }
    src_l[e] = s; dst_l[e] = d; valid_l[e] = (mk != 0) && (r == (m & 1));
  }
  for (int idx = tid; idx < 32 * 320; idx += 256)
    adus_l[idx / 320][idx % 320] = adus_ws[(size_t)c * 10240 + idx];
  __syncthreads();

  if (tid < 96) {
    int a = tid & 31, k = tid >> 5;
    const float* alp = alproj + (m * 3 + k) * 320;
    const float* arp = arproj + (m * 3 + k) * 320;
    float sa = 0.f, sb = 0.f;
    for (int d = 0; d < 320; ++d) {
      float v = adus_l[a][d];
      sa += v * alp[d];
      sb += v * arp[d];
    }
    sl_l[a * 3 + k] = sa;
    sr_l[a * 3 + k] = sb;
  }
  __syncthreads();
  if (tid < 144) {
    int e = tid % 48, k = tid / 48;
    float v = -1e30f;
    if (valid_l[e]) v = lreluf(sl_l[src_l[e] * 3 + k] + sr_l[dst_l[e] * 3 + k]);
    e_l[e * 3 + k] = v;
  }
  __syncthreads();
  if (tid < 96) {
    int a = tid & 31, k = tid >> 5;
    float mx = -1e30f;
    for (int e = 0; e < 48; ++e)
      if (valid_l[e] && dst_l[e] == a) mx = fmaxf(mx, e_l[e * 3 + k]);
    float den = 0.f;
    for (int e = 0; e < 48; ++e)
      if (valid_l[e] && dst_l[e] == a) den += __expf(e_l[e * 3 + k] - mx);
    mx_l[a * 3 + k] = mx;
    den_l[a * 3 + k] = den;
  }
  __syncthreads();
  if (tid < 144) {
    int e = tid % 48, k = tid / 48;
    float v = 0.f;
    if (valid_l[e]) {
      int d = dst_l[e];
      v = __expf(e_l[e * 3 + k] - mx_l[d * 3 + k]) / fmaxf(den_l[d * 3 + k], 1e-9f);
    }
    alpha_l[e * 3 + k] = v;
  }
  __syncthreads();

  const int ag = tid >> 3, og = tid & 7;
  const int dd_ = tid >> 4, oq_ = (tid & 15) * 4;
  for (int k = 0; k < 3; ++k) {
    for (int ot = 0; ot < 4; ++ot) {
      float acc[8];
#pragma unroll
      for (int i = 0; i < 8; ++i) acc[i] = 0.f;
      float4 pref = *(const float4*)(Wgat + ((size_t)((m * 3 + k) * 320 + dd_)) * 256 + ot * 64 + oq_);
      for (int dt = 0; dt < 320; dt += 16) {
        Wst[dd_][oq_ + 0] = pref.x;
        Wst[dd_][oq_ + 1] = pref.y;
        Wst[dd_][oq_ + 2] = pref.z;
        Wst[dd_][oq_ + 3] = pref.w;
        __syncthreads();
        if (dt + 16 < 320)
          pref = *(const float4*)(Wgat +
                                  ((size_t)((m * 3 + k) * 320 + dt + 16 + dd_)) * 256 + ot * 64 + oq_);
#pragma unroll
        for (int dd = 0; dd < 16; ++dd) {
          float av = adus_l[ag][dt + dd];
          const float4 w0 = *(const float4*)(&Wst[dd][og * 8]);
          const float4 w1 = *(const float4*)(&Wst[dd][og * 8 + 4]);
          acc[0] += av * w0.x; acc[1] += av * w0.y; acc[2] += av * w0.z; acc[3] += av * w0.w;
          acc[4] += av * w1.x; acc[5] += av * w1.y; acc[6] += av * w1.z; acc[7] += av * w1.w;
        }
        __syncthreads();
      }
#pragma unroll
      for (int i = 0; i < 8; ++i) hp_t[ag][og * 8 + i] = acc[i];
      __syncthreads();
      float oacc[8];
#pragma unroll
      for (int i = 0; i < 8; ++i) oacc[i] = 0.f;
      for (int e = 0; e < 48; ++e) {
        if (valid_l[e] && dst_l[e] == ag) {
          float alv = alpha_l[e * 3 + k];
          int s = src_l[e];
#pragma unroll
          for (int i = 0; i < 8; ++i) oacc[i] += alv * hp_t[s][og * 8 + i];
        }
      }
#pragma unroll
      for (int i = 0; i < 8; ++i) {
        int o = ot * 64 + og * 8 + i;
        float v = eluf(oacc[i] + bgat[(m * 3 + k) * 256 + o]);
        zgat[((size_t)(c * 4 + m) * 32 + ag) * 768 + k * 256 + o] = v;
      }
      __syncthreads();
    }
  }
}

// ---------- K3w: semantic attention ----------
__global__ __launch_bounds__(256) void k_sem(const float* __restrict__ zgat,
                                             const float* __restrict__ Wsem,
                                             const float* __restrict__ bsem,
                                             const float* __restrict__ qsem,
                                             const void* __restrict__ amask,
                                             float* __restrict__ wsem) {
  __shared__ float Wst[64][128];
  __shared__ float zl[32][64];
  __shared__ float wred[256];
  __shared__ float war[32];
  const int c = blockIdx.x >> 2, m = blockIdx.x & 3;
  const int tid = threadIdx.x;
  const int mb = maskmode(amask);
  const int a = tid >> 3, hg = tid & 7;
  float acc[16];
#pragma unroll
  for (int i = 0; i < 16; ++i) acc[i] = 0.f;
  const float* zbase = zgat + (size_t)(c * 4 + m) * 32 * 768;
  for (int jt = 0; jt < 768; jt += 64) {
    for (int l = 0; l < 8; ++l) {
      int f4 = l * 256 + tid;
      int row = f4 >> 5, c4 = (f4 & 31) * 4;
      *(float4*)&Wst[row][c4] = *(const float4*)(Wsem + (size_t)(jt + row) * 128 + c4);
    }
    for (int l = 0; l < 2; ++l) {
      int f4 = l * 256 + tid;
      int row = f4 >> 4, c4 = (f4 & 15) * 4;
      *(float4*)&zl[row][c4] = *(const float4*)(zbase + (size_t)row * 768 + jt + c4);
    }
    __syncthreads();
    for (int j = 0; j < 64; ++j) {
      float zv = zl[a][j];
      const float* wp = &Wst[j][hg * 16];
#pragma unroll
      for (int i = 0; i < 16; ++i) acc[i] += zv * wp[i];
    }
    __syncthreads();
  }
  float wp_ = 0.f;
#pragma unroll
  for (int i = 0; i < 16; ++i) {
    int h = hg * 16 + i;
    wp_ += tanhf_fast(acc[i] + bsem[h]) * qsem[h];
  }
  wred[tid] = wp_;
  __syncthreads();
  if (tid < 32) {
    float s = 0.f;
    for (int q = 0; q < 8; ++q) s += wred[tid * 8 + q];
    war[tid] = s;
  }
  __syncthreads();
  if (tid == 0) {
    float s = 0.f;
    int cnt = 0;
    for (int aa = 0; aa < 32; ++aa)
      if (ldmask(amask, c * 32 + aa, mb)) { s += war[aa]; cnt++; }
    wsem[c * 4 + m] = s / (float)(cnt > 1 ? cnt : 1);
  }
}

// ---------- K3b: per-comment assembly. Weights staged in LDS (wbuf 53KB). ----------
__global__ __launch_bounds__(256) void k_comment(
    const float* __restrict__ zgat, const float* __restrict__ wsem,
    const float* __restrict__ cemb_ws, const float* __restrict__ Wpred,
    const float* __restrict__ bpred, const float* __restrict__ Wadu1,
    const float* __restrict__ badu1, const float* __restrict__ Wadu2,
    const float* __restrict__ badu2, const float* __restrict__ Winn1,
    const float* __restrict__ binn1, const float* __restrict__ Winn2,
    const float* __restrict__ binn2, const float* __restrict__ Wint1,
    const float* __restrict__ bint1, const float* __restrict__ Wint2,
    const float* __restrict__ bint2, const float* __restrict__ info,
    const void* __restrict__ amask, const void* __restrict__ lmask,
    const int* __restrict__ isrc, const int* __restrict__ idst,
    const int* __restrict__ irel, const void* __restrict__ imask, const int* __restrict__ tsrc,
    const int* __restrict__ tdst, const int* __restrict__ trel, const void* __restrict__ tmask,
    float* __restrict__ woctx, float* __restrict__ dout) {
  __shared__ float zf[32][133];
  __shared__ float ae[32][257];
  __shared__ float wbuf[13344];
  __shared__ float cemb_l[320];
  __shared__ float beta_l[4];
  __shared__ float pred_l[48][16];
  __shared__ float sE[48], alE[48];
  __shared__ int seL[48], deL[48], relL[48], mskL[48];
  __shared__ float wredA[256];
  __shared__ float sA[32], alA[32];
  __shared__ int mskA[32];
  const int c = blockIdx.x, tid = threadIdx.x;
  const int mb = maskmode(amask);

  if (tid == 0) {
    float w0 = wsem[c * 4], w1 = wsem[c * 4 + 1], w2 = wsem[c * 4 + 2], w3 = wsem[c * 4 + 3];
    float mx = fmaxf(fmaxf(w0, w1), fmaxf(w2, w3));
    float e0 = __expf(w0 - mx), e1 = __expf(w1 - mx), e2 = __expf(w2 - mx), e3 = __expf(w3 - mx);
    float s = e0 + e1 + e2 + e3;
    beta_l[0] = e0 / s; beta_l[1] = e1 / s; beta_l[2] = e2 / s; beta_l[3] = e3 / s;
  }
  for (int d = tid; d < 320; d += 256) cemb_l[d] = cemb_ws[c * 320 + d];
  __syncthreads();

  const int ag = tid >> 5;
  const int og = tid & 31;
  float acc[4][8];
#pragma unroll
  for (int i = 0; i < 4; ++i)
#pragma unroll
    for (int j = 0; j < 8; ++j) acc[i][j] = 0.f;
  const float b0 = beta_l[0], b1 = beta_l[1], b2 = beta_l[2], b3 = beta_l[3];
  const float* zc0 = zgat + (size_t)(c * 4 + 0) * 32 * 768;
  const float* zc1 = zgat + (size_t)(c * 4 + 1) * 32 * 768;
  const float* zc2 = zgat + (size_t)(c * 4 + 2) * 32 * 768;
  const float* zc3 = zgat + (size_t)(c * 4 + 3) * 32 * 768;
  for (int jt = 0; jt < 768; jt += 128) {
    for (int l = 0; l < 16; ++l) {
      int idx = l * 256 + tid;
      int a = idx >> 7, j = idx & 127;
      size_t off = (size_t)a * 768 + jt + j;
      zf[a][j] = b0 * zc0[off] + b1 * zc1[off] + b2 * zc2[off] + b3 * zc3[off];
    }
    __syncthreads();
    const float* wp0 = Wpred + (size_t)jt * 256 + og * 8;
    float4 w0v = *(const float4*)wp0;
    float4 w1v = *(const float4*)(wp0 + 4);
    for (int j = 0; j < 128; ++j) {
      float4 n0v, n1v;
      if (j + 1 < 128) {
        const float* wp = Wpred + (size_t)(jt + j + 1) * 256 + og * 8;
        n0v = *(const float4*)wp;
        n1v = *(const float4*)(wp + 4);
      }
      float w8[8] = {w0v.x, w0v.y, w0v.z, w0v.w, w1v.x, w1v.y, w1v.z, w1v.w};
      float z0 = zf[ag * 4 + 0][j], z1 = zf[ag * 4 + 1][j];
      float z2 = zf[ag * 4 + 2][j], z3 = zf[ag * 4 + 3][j];
#pragma unroll
      for (int jj = 0; jj < 8; ++jj) {
        acc[0][jj] += z0 * w8[jj];
        acc[1][jj] += z1 * w8[jj];
        acc[2][jj] += z2 * w8[jj];
        acc[3][jj] += z3 * w8[jj];
      }
      if (j + 1 < 128) { w0v = n0v; w1v = n1v; }
    }
    __syncthreads();
  }
#pragma unroll
  for (int i = 0; i < 4; ++i)
#pragma unroll
    for (int jj = 0; jj < 8; ++jj)
      ae[ag * 4 + i][og * 8 + jj] = acc[i][jj] + bpred[og * 8 + jj];
  for (int idx = tid; idx < 9216; idx += 256) wbuf[idx] = Wadu1[idx];
  __syncthreads();

  {
    const int a = tid >> 3, hg = tid & 7;
    float sacc = 0.f;
    for (int hh = 0; hh < 2; ++hh) {
      int h = hg * 2 + hh;
      float d = badu1[h];
      for (int dd = 0; dd < 320; ++dd) d += cemb_l[dd] * wbuf[dd * 16 + h];
      for (int dd = 0; dd < 256; ++dd) d += ae[a][dd] * wbuf[(320 + dd) * 16 + h];
      sacc += fmaxf(d, 0.f) * Wadu2[h];
    }
    wredA[tid] = sacc;
  }
  __syncthreads();
  if (tid < 32) {
    float s = badu2[0];
    for (int q = 0; q < 8; ++q) s += wredA[tid * 8 + q];
    sA[tid] = s;
    mskA[tid] = (ldmask(amask, c * 32 + tid, mb) != 0) && (ldmask(lmask, c * 32 + tid, mb) != 0);
  }
  __syncthreads();
  if (tid == 0) {
    float mx = -1e30f;
    int any = 0;
    for (int a = 0; a < 32; ++a)
      if (mskA[a]) { any = 1; mx = fmaxf(mx, sA[a]); }
    float s = 0.f;
    for (int a = 0; a < 32; ++a) {
      float v = mskA[a] ? __expf(sA[a] - mx) : 0.f;
      alA[a] = v;
      s += v;
    }
    if (any)
      for (int a = 0; a < 32; ++a) alA[a] /= s;
  }
  __syncthreads();
  {
    int o = tid;
    float v = 0.f;
    for (int a = 0; a < 32; ++a) v += alA[a] * ae[a][o];
    woctx[c * 1608 + o] = v;
    dout[(size_t)c * 1808 + 200 + o] = v;
  }
  __syncthreads();

  for (int pp = 0; pp < 2; ++pp) {
    const float *W1, *b1v, *W2, *b2v;
    const int *seP, *deP, *relP;
    const void* mskP;
    int outoff;
    if (pp == 0) {
      W1 = Winn1; b1v = binn1; W2 = Winn2; b2v = binn2;
      seP = isrc; deP = idst; relP = irel; mskP = imask; outoff = 256;
    } else {
      W1 = Wint1; b1v = bint1; W2 = Wint2; b2v = bint2;
      seP = tdst; deP = tsrc; relP = trel; mskP = tmask; outoff = 770;
    }
    if (tid < 48) {
      seL[tid] = seP[c * 48 + tid];
      deL[tid] = deP[c * 48 + tid];
      relL[tid] = relP[c * 48 + tid];
      mskL[tid] = (ldmask(mskP, c * 48 + tid, mb) != 0);
    }
    for (int idx = tid; idx < 13344; idx += 256) wbuf[idx] = W1[idx];
    __syncthreads();
    for (int u = tid; u < 768; u += 256) {
      int e = u >> 4, h = u & 15;
      int se = seL[e], de = deL[e];
      float rel = (float)relL[e];
      float d = b1v[h];
      for (int dd = 0; dd < 320; ++dd) d += cemb_l[dd] * wbuf[dd * 16 + h];
      for (int dd = 0; dd < 256; ++dd) d += ae[se][dd] * wbuf[(320 + dd) * 16 + h];
      for (int dd = 0; dd < 256; ++dd) d += ae[de][dd] * wbuf[(576 + dd) * 16 + h];
      d += rel * wbuf[832 * 16 + h] + (1.f - rel) * wbuf[833 * 16 + h];
      pred_l[e][h] = fmaxf(d, 0.f) * W2[h];
    }
    __syncthreads();
    if (tid < 48) {
      float s = b2v[0];
      for (int h = 0; h < 16; ++h) s += pred_l[tid][h];
      sE[tid] = s;
    }
    __syncthreads();
    if (tid == 0) {
      float mx = -1e30f;
      int any = 0;
      for (int e = 0; e < 48; ++e)
        if (mskL[e]) { any = 1; mx = fmaxf(mx, sE[e]); }
      float s = 0.f;
      for (int e = 0; e < 48; ++e) {
        float v = mskL[e] ? __expf(sE[e] - mx) : 0.f;
        alE[e] = v;
        s += v;
      }
      if (any)
        for (int e = 0; e < 48; ++e) alE[e] /= s;
    }
    __syncthreads();
    for (int dim = tid; dim < 514; dim += 256) {
      float v = 0.f;
      for (int e = 0; e < 48; ++e) {
        float alv = alE[e];
        float pe;
        if (dim < 256) pe = ae[seL[e]][dim];
        else if (dim < 512) pe = ae[deL[e]][dim - 256];
        else if (dim == 512) pe = (float)relL[e];
        else pe = 1.f - (float)relL[e];
        v += alv * pe;
      }
      woctx[c * 1608 + outoff + dim] = v;
      dout[(size_t)c * 1808 + 200 + outoff + dim] = v;
    }
    __syncthreads();
  }

  if (tid < 4) {
    float v = info[c * 4 + tid];
    woctx[c * 1608 + 1284 + tid] = v;
    dout[(size_t)c * 1808 + 200 + 1284 + tid] = v;
  }
  for (int d = tid; d < 320; d += 256) {
    float v = cemb_l[d];
    woctx[c * 1608 + 1288 + d] = v;
    dout[(size_t)c * 1808 + 200 + 1288 + d] = v;
  }
}

// ---------- K4a: ctx LSTM input projection ----------
__global__ __launch_bounds__(256) void k_ctx_in(const float* __restrict__ woctx,
                                                const float* __restrict__ Wihc,
                                                const float* __restrict__ bc,
                                                float* __restrict__ xc) {
  __shared__ float woc[64][133];
  __shared__ float Wst[8][128];
  const int r0 = blockIdx.x * 8;
  const int tid = threadIdx.x;
  const int t = tid & 63, rg = tid >> 6;
  float a0 = 0.f, a1 = 0.f;
  for (int d0 = 0; d0 < 1608; d0 += 128) {
    int jn = 1608 - d0;
    if (jn > 128) jn = 128;
    for (int l = 0; l < 32; ++l) {
      int idx = l * 256 + tid;
      int tt = idx >> 7, j = idx & 127;
      woc[tt][j] = (j < jn) ? woctx[(size_t)tt * 1608 + d0 + j] : 0.f;
    }
    {
      int rr = tid >> 5, jb = tid & 31;
      for (int q = 0; q < 4; ++q) {
        int jj = jb * 4 + q;
        Wst[rr][jj] = (jj < jn) ? Wihc[(size_t)(r0 + rr) * 1608 + d0 + jj] : 0.f;
      }
    }
    __syncthreads();
    for (int j = 0; j < 128; ++j) {
      float x = woc[t][j];
      a0 += x * Wst[rg * 2 + 0][j];
      a1 += x * Wst[rg * 2 + 1][j];
    }
    __syncthreads();
  }
  int r = r0 + rg * 2;
  xc[t * 800 + r] = a0 + bc[r];
  xc[t * 800 + r + 1] = a1 + bc[r + 1];
}

// ---------- K4b: ctx LSTM recurrence ----------
__global__ __launch_bounds__(832) void k_ctx_rec(const float* __restrict__ xc,
                                                 const uint4* __restrict__ wt4,
                                                 float* __restrict__ dout) {
  __shared__ alignas(16) u32 hl2[100];
  __shared__ float zc[800];
  const int tid = threadIdx.x;
  if (tid < 100) hl2[tid] = 0;
  float cst = 0.f;
  __syncthreads();
  for (int t = 0; t < 64; ++t) {
    if (tid < 800) {
      float a0 = xc[t * 800 + tid], a1 = 0.f, a2 = 0.f, a3 = 0.f;
#pragma unroll 5
      for (int k4 = 0; k4 < 25; ++k4) {
        uint4 wv = wt4[(size_t)k4 * 800 + tid];
        uint4 hq = *(const uint4*)&hl2[k4 * 4];
        a0 = dot2h(wv.x, hq.x, a0);
        a1 = dot2h(wv.y, hq.y, a1);
        a2 = dot2h(wv.z, hq.z, a2);
        a3 = dot2h(wv.w, hq.w, a3);
      }
      zc[tid] = (a0 + a1) + (a2 + a3);
    }
    __syncthreads();
    if (tid < 200) {
      float iv = sigf(zc[tid]);
      float fv = sigf(zc[200 + tid]);
      float gv = tanhf_fast(zc[400 + tid]);
      float ov = sigf(zc[600 + tid]);
      cst = fv * cst + iv * gv;
      float h = ov * tanhf_fast(cst);
      ((u16*)hl2)[tid] = __half_as_ushort(__float2half(h));
      dout[(size_t)t * 1808 + tid] = h;
    }
    __syncthreads();
  }
}

// ---------- launch ----------
extern "C" void kernel_launch(void* const* d_in, const int* in_sizes, int n_in, void* d_out,
                              int out_size, void* d_ws, size_t ws_size, hipStream_t stream) {
  const float* emb = (const float*)d_in[0];
  const float* info = (const float*)d_in[1];
  const int* cspan = (const int*)d_in[2];
  const int* aspan = (const int*)d_in[3];
  const void* amask = d_in[4];
  const void* lmask = d_in[5];
  const int* isrc = (const int*)d_in[6];
  const int* idst = (const int*)d_in[7];
  const int* irel = (const int*)d_in[8];
  const void* imask = d_in[9];
  const int* tsrc = (const int*)d_in[10];
  const int* tdst = (const int*)d_in[11];
  const int* trel = (const int*)d_in[12];
  const void* tmask = d_in[13];
  const float* Wihf = (const float*)d_in[14];
  const float* Whhf = (const float*)d_in[15];
  const float* bfv = (const float*)d_in[16];
  const float* Wihb = (const float*)d_in[17];
  const float* Whhb = (const float*)d_in[18];
  const float* bbv = (const float*)d_in[19];
  const float* Wgat = (const float*)d_in[20];
  const float* al = (const float*)d_in[21];
  const float* ar = (const float*)d_in[22];
  const float* bgat = (const float*)d_in[23];
  const float* Wsem = (const float*)d_in[24];
  const float* bsem = (const float*)d_in[25];
  const float* qsem = (const float*)d_in[26];
  const float* Wpred = (const float*)d_in[27];
  const float* bpred = (const float*)d_in[28];
  const float* Wadu1 = (const float*)d_in[29];
  const float* badu1 = (const float*)d_in[30];
  const float* Wadu2 = (const float*)d_in[31];
  const float* badu2 = (const float*)d_in[32];
  const float* Winn1 = (const float*)d_in[33];
  const float* binn1 = (const float*)d_in[34];
  const float* Winn2 = (const float*)d_in[35];
  const float* binn2 = (const float*)d_in[36];
  const float* Wint1 = (const float*)d_in[37];
  const float* bint1 = (const float*)d_in[38];
  const float* Wint2 = (const float*)d_in[39];
  const float* bint2 = (const float*)d_in[40];
  const float* Wihc = (const float*)d_in[41];
  const float* Whhc = (const float*)d_in[42];
  const float* bc = (const float*)d_in[43];
  float* out = (float*)d_out;
  float* ws = (float*)d_ws;

  const size_t OFF_Z = 0;                                    // 65536*640
  const size_t OFF_HF = OFF_Z + (size_t)65536 * 640;         // 64*1024*80
  const size_t OFF_HB = OFF_HF + (size_t)64 * 1024 * 80;
  const size_t OFF_ZG = OFF_HB + (size_t)64 * 1024 * 80;     // 64*4*32*768
  const size_t OFF_AD = OFF_ZG + (size_t)64 * 4 * 32 * 768;  // 64*32*320
  const size_t OFF_CE = OFF_AD + (size_t)64 * 32 * 320;      // 64*320
  const size_t OFF_WS4 = OFF_CE + 64 * 320;                  // 256
  const size_t OFF_ALP = OFF_WS4 + 256;                      // 3840
  const size_t OFF_ARP = OFF_ALP + 3840;                     // 3840
  const size_t OFF_WO = OFF_ARP + 3840;                      // 64*1608
  const size_t OFF_XC = OFF_WO + (size_t)64 * 1608;          // 64*800
  const size_t OFF_WT = OFF_XC + (size_t)64 * 800;           // 80000 u32
  const size_t TOTAL = OFF_WT + 80000;

  if (n_in < 44 || ws_size < TOTAL * sizeof(float)) {
    k_marker<<<1, 1, 0, stream>>>(out);
    return;
  }

  k_prep<<<960, 256, 0, stream>>>(Wgat, al, ar, ws + OFF_ALP, ws + OFF_ARP);
  k_pack<<<79, 256, 0, stream>>>(Whhc, (uint4*)(ws + OFF_WT));
  dim3 g1(5, 512);  // n-tiles fastest: 5 consecutive blocks reuse one A-panel
  k_gemm_in<<<g1, 256, 0, stream>>>(emb, Wihf, Wihb, bfv, bbv, ws + OFF_Z);
  k_lstm_tok<<<128, 320, 0, stream>>>(ws + OFF_Z, Whhf, Whhb, ws + OFF_HF, ws + OFF_HB);
  k_span<<<64, 256, 0, stream>>>(ws + OFF_HF, ws + OFF_HB, cspan, aspan, amask, ws + OFF_AD,
                                 ws + OFF_CE);
  k_gat<<<256, 256, 0, stream>>>(ws + OFF_AD, ws + OFF_ALP, ws + OFF_ARP, Wgat, bgat, isrc, idst,
                                 irel, imask, tsrc, tdst, trel, tmask, amask, ws + OFF_ZG);
  k_sem<<<256, 256, 0, stream>>>(ws + OFF_ZG, Wsem, bsem, qsem, amask, ws + OFF_WS4);
  k_comment<<<64, 256, 0, stream>>>(ws + OFF_ZG, ws + OFF_WS4, ws + OFF_CE, Wpred, bpred, Wadu1,
                                    badu1, Wadu2, badu2, Winn1, binn1, Winn2, binn2, Wint1, bint1,
                                    Wint2, bint2, info, amask, lmask, isrc, idst, irel, imask,
                                    tsrc, tdst, trel, tmask, ws + OFF_WO, out);
  k_ctx_in<<<100, 256, 0, stream>>>(ws + OFF_WO, Wihc, bc, ws + OFF_XC);
  k_ctx_rec<<<1, 832, 0, stream>>>(ws + OFF_XC, (const uint4*)(ws + OFF_WT), out);
}

// Round 15
// 1683.091 us; speedup vs baseline: 1.0954x; 1.0954x over previous
//
#include <hip/hip_runtime.h>
#include <hip/hip_bf16.h>
#include <hip/hip_fp16.h>
#include <stdint.h>

typedef unsigned int u32;
typedef unsigned short u16;
typedef __attribute__((ext_vector_type(8))) short short8;
typedef __attribute__((ext_vector_type(4))) float f32x4;
typedef _Float16 half2v __attribute__((ext_vector_type(2)));

#if defined(__has_builtin)
#if __has_builtin(__builtin_amdgcn_fdot2)
#define HAVE_FDOT2 1
#endif
#endif

// ---------- helpers ----------
__device__ __forceinline__ float bf2f_u(u32 lo16) { return __uint_as_float(lo16 << 16); }
__device__ __forceinline__ u32 f2bf_bits(float x) {
  u32 u = __float_as_uint(x);
  return (u + 0x7fffu + ((u >> 16) & 1u)) >> 16;
}
__device__ __forceinline__ u32 pk2bf_tr(float x, float y) {  // truncating pack, 2 VALU
  return (__float_as_uint(y) & 0xffff0000u) | (__float_as_uint(x) >> 16);
}
__device__ __forceinline__ u32 pkh(float x, float y) {  // two f16 in a u32
  return (u32)__half_as_ushort(__float2half(x)) |
         ((u32)__half_as_ushort(__float2half(y)) << 16);
}
__device__ __forceinline__ float dot2h(u32 w, u32 h, float acc) {
#ifdef HAVE_FDOT2
  return __builtin_amdgcn_fdot2(__builtin_bit_cast(half2v, w), __builtin_bit_cast(half2v, h),
                                acc, false);
#else
  union { u32 u; __half2 h2; } uw, uh;
  uw.u = w; uh.u = h;
  float2 wf = __half22float2(uw.h2);
  float2 hf = __half22float2(uh.h2);
  return acc + wf.x * hf.x + wf.y * hf.y;
#endif
}
__device__ __forceinline__ float sigf(float x) { return 1.0f / (1.0f + __expf(-x)); }
__device__ __forceinline__ float tanhf_fast(float x) {
  float ax = fabsf(x);
  float e = __expf(-2.0f * ax);
  float t = (1.0f - e) / (1.0f + e);
  return x < 0.0f ? -t : t;
}
__device__ __forceinline__ float eluf(float x) { return x > 0.0f ? x : __expf(x) - 1.0f; }
__device__ __forceinline__ float lreluf(float x) { return x > 0.0f ? x : 0.2f * x; }

__device__ __forceinline__ int maskmode(const void* am) { return (*(const u32*)am) > 0xFFu; }
__device__ __forceinline__ int ldmask(const void* p, int i, int mb) {
  return mb ? (int)((const unsigned char*)p)[i] : ((const int*)p)[i];
}

__global__ void k_marker(float* out) { out[0] = 12345.0f; }

// ---------- K0: precompute W_gat @ a_l / a_r (wave-per-output, coalesced) ----------
__global__ __launch_bounds__(256) void k_prep(const float* __restrict__ Wgat,
                                              const float* __restrict__ al,
                                              const float* __restrict__ ar,
                                              float* __restrict__ alproj,
                                              float* __restrict__ arproj) {
  int w = blockIdx.x * 4 + (threadIdx.x >> 6);
  int lane = threadIdx.x & 63;
  if (w >= 3840) return;
  int mk = w / 320, d = w % 320;
  const float* wrow = Wgat + ((size_t)mk * 320 + d) * 256;
  const float* alp = al + mk * 256;
  const float* arp = ar + mk * 256;
  float sa = 0.f, sb = 0.f;
#pragma unroll
  for (int q = 0; q < 4; ++q) {
    int o = lane + q * 64;
    float wv = wrow[o];
    sa += wv * alp[o];
    sb += wv * arp[o];
  }
#pragma unroll
  for (int off = 32; off; off >>= 1) {
    sa += __shfl_down(sa, off, 64);
    sb += __shfl_down(sb, off, 64);
  }
  if (lane == 0) { alproj[w] = sa; arproj[w] = sb; }
}

// ---------- K0b: Whh_c -> wt4[k4][800] uint4 of f16 pairs ----------
__global__ void k_pack(const float* __restrict__ whhc, uint4* __restrict__ wt4) {
  int idx = blockIdx.x * 256 + threadIdx.x;
  if (idx >= 20000) return;
  int k4 = idx / 800, r = idx % 800;
  const float* p = whhc + r * 200 + k4 * 8;
  wt4[idx] = (uint4){pkh(p[0], p[1]), pkh(p[2], p[3]), pkh(p[4], p[5]), pkh(p[6], p[7])};
}

// ---------- K1: input GEMM (MFMA bf16), trunc pack-in-loop, plain Z[m][640] ----------
__global__ __launch_bounds__(256) void k_gemm_in(
    const float* __restrict__ emb, const float* __restrict__ Wf, const float* __restrict__ Wb,
    const float* __restrict__ biasf, const float* __restrict__ biasb, float* __restrict__ Z) {
  __shared__ u16 Albs[128 * 40];
  __shared__ u16 Blbs[128 * 40];
  __shared__ float bias_l[128];
  const int tid = threadIdx.x;
  const int n0 = blockIdx.x * 128;
  const int m0 = blockIdx.y * 128;

  if (tid < 128) {
    int ng = n0 + tid;
    bias_l[tid] = (ng < 320) ? biasf[ng] : biasb[ng - 320];
  }
  const int srow = tid >> 1, shalf = tid & 1;
  const float* asrc = emb + (size_t)(m0 + srow) * 768 + shalf * 16;
  const int ngb = n0 + srow;
  const float* bsrc =
      ((ngb < 320) ? (Wf + (size_t)ngb * 768) : (Wb + (size_t)(ngb - 320) * 768)) + shalf * 16;
  u32* aw = (u32*)&Albs[srow * 40 + shalf * 16];
  u32* bw = (u32*)&Blbs[srow * 40 + shalf * 16];

  const int lane = tid & 63;
  const int lr = lane & 15, sub = lane >> 4;
  const int wv = tid >> 6, wm = wv >> 1, wn = wv & 1;
  const u16* abase = &Albs[(wm * 64 + lr) * 40 + sub * 8];
  const u16* bbase = &Blbs[(wn * 64 + lr) * 40 + sub * 8];

  f32x4 acc[4][4];
#pragma unroll
  for (int i = 0; i < 4; ++i)
#pragma unroll
    for (int j = 0; j < 4; ++j) acc[i][j] = (f32x4)(0.f);

  float4 a0, a1, a2, a3, b0, b1, b2, b3;
  u32 pra[8], prb[8];
  a0 = *(const float4*)(asrc + 0); a1 = *(const float4*)(asrc + 4);
  a2 = *(const float4*)(asrc + 8); a3 = *(const float4*)(asrc + 12);
  b0 = *(const float4*)(bsrc + 0); b1 = *(const float4*)(bsrc + 4);
  b2 = *(const float4*)(bsrc + 8); b3 = *(const float4*)(bsrc + 12);
  pra[0] = pk2bf_tr(a0.x, a0.y); pra[1] = pk2bf_tr(a0.z, a0.w);
  pra[2] = pk2bf_tr(a1.x, a1.y); pra[3] = pk2bf_tr(a1.z, a1.w);
  pra[4] = pk2bf_tr(a2.x, a2.y); pra[5] = pk2bf_tr(a2.z, a2.w);
  pra[6] = pk2bf_tr(a3.x, a3.y); pra[7] = pk2bf_tr(a3.z, a3.w);
  prb[0] = pk2bf_tr(b0.x, b0.y); prb[1] = pk2bf_tr(b0.z, b0.w);
  prb[2] = pk2bf_tr(b1.x, b1.y); prb[3] = pk2bf_tr(b1.z, b1.w);
  prb[4] = pk2bf_tr(b2.x, b2.y); prb[5] = pk2bf_tr(b2.z, b2.w);
  prb[6] = pk2bf_tr(b3.x, b3.y); prb[7] = pk2bf_tr(b3.z, b3.w);

  for (int it = 0; it < 24; ++it) {
    __syncthreads();
#pragma unroll
    for (int q = 0; q < 8; ++q) { aw[q] = pra[q]; bw[q] = prb[q]; }
    __syncthreads();
    const bool more = (it + 1 < 24);
    if (more) {
      const int k0 = (it + 1) * 32;
      a0 = *(const float4*)(asrc + k0); a1 = *(const float4*)(asrc + k0 + 4);
      a2 = *(const float4*)(asrc + k0 + 8); a3 = *(const float4*)(asrc + k0 + 12);
      b0 = *(const float4*)(bsrc + k0); b1 = *(const float4*)(bsrc + k0 + 4);
      b2 = *(const float4*)(bsrc + k0 + 8); b3 = *(const float4*)(bsrc + k0 + 12);
    }
    short8 bfr[4];
#pragma unroll
    for (int nf = 0; nf < 4; ++nf) bfr[nf] = *(const short8*)(bbase + nf * 640);
#pragma unroll
    for (int mf = 0; mf < 4; ++mf) {
      short8 af = *(const short8*)(abase + mf * 640);
#pragma unroll
      for (int nf = 0; nf < 4; ++nf)
        acc[mf][nf] = __builtin_amdgcn_mfma_f32_16x16x32_bf16(af, bfr[nf], acc[mf][nf], 0, 0, 0);
    }
    if (more) {
      pra[0] = pk2bf_tr(a0.x, a0.y); pra[1] = pk2bf_tr(a0.z, a0.w);
      pra[2] = pk2bf_tr(a1.x, a1.y); pra[3] = pk2bf_tr(a1.z, a1.w);
      pra[4] = pk2bf_tr(a2.x, a2.y); pra[5] = pk2bf_tr(a2.z, a2.w);
      pra[6] = pk2bf_tr(a3.x, a3.y); pra[7] = pk2bf_tr(a3.z, a3.w);
      prb[0] = pk2bf_tr(b0.x, b0.y); prb[1] = pk2bf_tr(b0.z, b0.w);
      prb[2] = pk2bf_tr(b1.x, b1.y); prb[3] = pk2bf_tr(b1.z, b1.w);
      prb[4] = pk2bf_tr(b2.x, b2.y); prb[5] = pk2bf_tr(b2.z, b2.w);
      prb[6] = pk2bf_tr(b3.x, b3.y); prb[7] = pk2bf_tr(b3.z, b3.w);
    }
  }
#pragma unroll
  for (int mf = 0; mf < 4; ++mf) {
#pragma unroll
    for (int nf = 0; nf < 4; ++nf) {
      int col = wn * 64 + nf * 16 + lr;
      float bias = bias_l[col];
      size_t mrow = (size_t)m0 + wm * 64 + mf * 16 + sub * 4;
#pragma unroll
      for (int j = 0; j < 4; ++j)
        Z[(mrow + j) * 640 + n0 + col] = acc[mf][nf][j] + bias;
    }
  }
}

// ---------- K2: token LSTM (round-12 exact: best measured 682us) ----------
__global__ __launch_bounds__(320, 1) void k_lstm_tok(const float* __restrict__ Z,
                                                     const float* __restrict__ Whhf,
                                                     const float* __restrict__ Whhb,
                                                     float* __restrict__ hf,
                                                     float* __restrict__ hb) {
  __shared__ uint2 wq[20 * 320];
  __shared__ alignas(16) u32 hpk[40];
  __shared__ float zbuf[320];
  const int tid = threadIdx.x;
  const int c = blockIdx.x >> 1;
  const int dir = blockIdx.x & 1;
  const float* Whh = dir ? Whhb : Whhf;
  float* hout = dir ? hb : hf;

  for (int idx = tid; idx < 20 * 320; idx += 320) {
    int k4 = idx / 320, r = idx % 320;
    const float* p = Whh + (size_t)r * 80 + k4 * 4;
    wq[idx] = (uint2){pkh(p[0], p[1]), pkh(p[2], p[3])};
  }
  if (tid < 40) hpk[tid] = 0;
  __syncthreads();

  const int j = tid;
  const uint2* wcol = wq + j;
  uint2 wv0 = wcol[0], wv1 = wcol[320], wv2 = wcol[640], wv3 = wcol[960];
  uint2 wv4 = wcol[1280], wv5 = wcol[1600], wv6 = wcol[1920], wv7 = wcol[2240];
  uint2 wv8 = wcol[2560], wv9 = wcol[2880], wv10 = wcol[3200], wv11 = wcol[3520];
  uint2 wv12 = wcol[3840], wv13 = wcol[4160], wv14 = wcol[4480], wv15 = wcol[4800];
  uint2 wv16 = wcol[5120], wv17 = wcol[5440], wv18 = wcol[5760], wv19 = wcol[6080];

  const int sgn = dir ? -1 : 1;
  const int t0 = dir ? 1023 : 0;
  const float* zb = Z + (size_t)c * 1024 * 640 + dir * 320 + j;
  float zc = zb[(size_t)t0 * 640];
  float zn = zb[(size_t)(t0 + sgn) * 640];
  float cst = 0.f;

  for (int t = 0; t < 1024; ++t) {
    const int tt = t0 + sgn * t;
    float zp = 0.f;
    if (t + 2 < 1024) zp = zb[(size_t)(t0 + sgn * (t + 2)) * 640];
    float a0 = zc, a1 = 0.f, a2 = 0.f, a3 = 0.f;
    {
      uint4 h0 = *(const uint4*)&hpk[0];
      a0 = dot2h(wv0.x, h0.x, a0); a1 = dot2h(wv0.y, h0.y, a1);
      a2 = dot2h(wv1.x, h0.z, a2); a3 = dot2h(wv1.y, h0.w, a3);
      uint4 h1 = *(const uint4*)&hpk[4];
      a0 = dot2h(wv2.x, h1.x, a0); a1 = dot2h(wv2.y, h1.y, a1);
      a2 = dot2h(wv3.x, h1.z, a2); a3 = dot2h(wv3.y, h1.w, a3);
      uint4 h2 = *(const uint4*)&hpk[8];
      a0 = dot2h(wv4.x, h2.x, a0); a1 = dot2h(wv4.y, h2.y, a1);
      a2 = dot2h(wv5.x, h2.z, a2); a3 = dot2h(wv5.y, h2.w, a3);
      uint4 h3 = *(const uint4*)&hpk[12];
      a0 = dot2h(wv6.x, h3.x, a0); a1 = dot2h(wv6.y, h3.y, a1);
      a2 = dot2h(wv7.x, h3.z, a2); a3 = dot2h(wv7.y, h3.w, a3);
      uint4 h4 = *(const uint4*)&hpk[16];
      a0 = dot2h(wv8.x, h4.x, a0); a1 = dot2h(wv8.y, h4.y, a1);
      a2 = dot2h(wv9.x, h4.z, a2); a3 = dot2h(wv9.y, h4.w, a3);
      uint4 h5 = *(const uint4*)&hpk[20];
      a0 = dot2h(wv10.x, h5.x, a0); a1 = dot2h(wv10.y, h5.y, a1);
      a2 = dot2h(wv11.x, h5.z, a2); a3 = dot2h(wv11.y, h5.w, a3);
      uint4 h6 = *(const uint4*)&hpk[24];
      a0 = dot2h(wv12.x, h6.x, a0); a1 = dot2h(wv12.y, h6.y, a1);
      a2 = dot2h(wv13.x, h6.z, a2); a3 = dot2h(wv13.y, h6.w, a3);
      uint4 h7 = *(const uint4*)&hpk[28];
      a0 = dot2h(wv14.x, h7.x, a0); a1 = dot2h(wv14.y, h7.y, a1);
      a2 = dot2h(wv15.x, h7.z, a2); a3 = dot2h(wv15.y, h7.w, a3);
      uint4 h8 = *(const uint4*)&hpk[32];
      a0 = dot2h(wv16.x, h8.x, a0); a1 = dot2h(wv16.y, h8.y, a1);
      a2 = dot2h(wv17.x, h8.z, a2); a3 = dot2h(wv17.y, h8.w, a3);
      uint4 h9 = *(const uint4*)&hpk[36];
      a0 = dot2h(wv18.x, h9.x, a0); a1 = dot2h(wv18.y, h9.y, a1);
      a2 = dot2h(wv19.x, h9.z, a2); a3 = dot2h(wv19.y, h9.w, a3);
    }
    zbuf[j] = (a0 + a1) + (a2 + a3);
    __syncthreads();
    if (j < 80) {
      float iv = sigf(zbuf[j]);
      float fv = sigf(zbuf[80 + j]);
      float gv = tanhf_fast(zbuf[160 + j]);
      float ov = sigf(zbuf[240 + j]);
      cst = fv * cst + iv * gv;
      float h = ov * tanhf_fast(cst);
      ((u16*)hpk)[j] = (u16)__half_as_ushort(__float2half(h));
      hout[((size_t)c * 1024 + tt) * 80 + j] = h;
    }
    zc = zn; zn = zp;
    __syncthreads();
  }
}

// ---------- span representation ----------
__device__ __forceinline__ float span_val(const float* __restrict__ hf,
                                          const float* __restrict__ hb, int c, int i, int j,
                                          int d) {
  size_t base = (size_t)c * 1024 * 80;
  if (d < 80) return hf[base + (size_t)j * 80 + d] - hf[base + (size_t)(i - 1) * 80 + d];
  if (d < 160) return hb[base + (size_t)i * 80 + (d - 80)] - hb[base + (size_t)(j + 1) * 80 + (d - 80)];
  if (d < 240) return hf[base + (size_t)(i - 1) * 80 + (d - 160)];
  return hb[base + (size_t)(j + 1) * 80 + (d - 240)];
}

__global__ __launch_bounds__(256) void k_span(const float* __restrict__ hf,
                                              const float* __restrict__ hb,
                                              const int* __restrict__ cspan,
                                              const int* __restrict__ aspan,
                                              const void* __restrict__ amask,
                                              float* __restrict__ adus, float* __restrict__ cembo) {
  const int c = blockIdx.x, tid = threadIdx.x;
  const int mb = maskmode(amask);
  int ci = cspan[c * 2], cj = cspan[c * 2 + 1];
  for (int d = tid; d < 320; d += 256) cembo[c * 320 + d] = span_val(hf, hb, c, ci, cj, d);
  for (int idx = tid; idx < 32 * 320; idx += 256) {
    int a = idx / 320, d = idx % 320;
    float v = 0.f;
    if (ldmask(amask, c * 32 + a, mb)) {
      int ai = aspan[(c * 32 + a) * 2], aj = aspan[(c * 32 + a) * 2 + 1];
      v = span_val(hf, hb, c, ai, aj, d);
    }
    adus[(size_t)c * 10240 + idx] = v;
  }
}

// ---------- K3a: GAT per (comment, metapath); Wst tile prefetch ----------
__global__ __launch_bounds__(256) void k_gat(
    const float* __restrict__ adus_ws, const float* __restrict__ alproj,
    const float* __restrict__ arproj, const float* __restrict__ Wgat,
    const float* __restrict__ bgat, const int* __restrict__ isrc, const int* __restrict__ idst,
    const int* __restrict__ irel, const void* __restrict__ imask, const int* __restrict__ tsrc,
    const int* __restrict__ tdst, const int* __restrict__ trel, const void* __restrict__ tmask,
    const void* __restrict__ amdet, float* __restrict__ zgat) {
  __shared__ float adus_l[32][321];
  __shared__ float Wst[16][64];
  __shared__ float hp_t[32][66];
  __shared__ float sl_l[96], sr_l[96];
  __shared__ float e_l[144], alpha_l[144], mx_l[96], den_l[96];
  __shared__ int src_l[48], dst_l[48], valid_l[48];
  const int c = blockIdx.x >> 2, m = blockIdx.x & 3;
  const int tid = threadIdx.x;
  const int mb = maskmode(amdet);

  if (tid < 48) {
    int e = tid, s, d, r, mk;
    if (m < 2) {
      s = isrc[c * 48 + e]; d = idst[c * 48 + e]; r = irel[c * 48 + e];
      mk = ldmask(imask, c * 48 + e, mb);
    } else {
      s = tdst[c * 48 + e]; d = tsrc[c * 48 + e]; r = trel[c * 48 + e];
      mk = ldmask(tmask, c * 48 + e, mb);
    }
    src_l[e] = s; dst_l[e] = d; valid_l[e] = (mk != 0) && (r == (m & 1));
  }
  for (int idx = tid; idx < 32 * 320; idx += 256)
    adus_l[idx / 320][idx % 320] = adus_ws[(size_t)c * 10240 + idx];
  __syncthreads();

  if (tid < 96) {
    int a = tid & 31, k = tid >> 5;
    const float* alp = alproj + (m * 3 + k) * 320;
    const float* arp = arproj + (m * 3 + k) * 320;
    float sa = 0.f, sb = 0.f;
    for (int d = 0; d < 320; ++d) {
      float v = adus_l[a][d];
      sa += v * alp[d];
      sb += v * arp[d];
    }
    sl_l[a * 3 + k] = sa;
    sr_l[a * 3 + k] = sb;
  }
  __syncthreads();
  if (tid < 144) {
    int e = tid % 48, k = tid / 48;
    float v = -1e30f;
    if (valid_l[e]) v = lreluf(sl_l[src_l[e] * 3 + k] + sr_l[dst_l[e] * 3 + k]);
    e_l[e * 3 + k] = v;
  }
  __syncthreads();
  if (tid < 96) {
    int a = tid & 31, k = tid >> 5;
    float mx = -1e30f;
    for (int e = 0; e < 48; ++e)
      if (valid_l[e] && dst_l[e] == a) mx = fmaxf(mx, e_l[e * 3 + k]);
    float den = 0.f;
    for (int e = 0; e < 48; ++e)
      if (valid_l[e] && dst_l[e] == a) den += __expf(e_l[e * 3 + k] - mx);
    mx_l[a * 3 + k] = mx;
    den_l[a * 3 + k] = den;
  }
  __syncthreads();
  if (tid < 144) {
    int e = tid % 48, k = tid / 48;
    float v = 0.f;
    if (valid_l[e]) {
      int d = dst_l[e];
      v = __expf(e_l[e * 3 + k] - mx_l[d * 3 + k]) / fmaxf(den_l[d * 3 + k], 1e-9f);
    }
    alpha_l[e * 3 + k] = v;
  }
  __syncthreads();

  const int ag = tid >> 3, og = tid & 7;
  const int dd_ = tid >> 4, oq_ = (tid & 15) * 4;
  for (int k = 0; k < 3; ++k) {
    for (int ot = 0; ot < 4; ++ot) {
      float acc[8];
#pragma unroll
      for (int i = 0; i < 8; ++i) acc[i] = 0.f;
      float4 pref = *(const float4*)(Wgat + ((size_t)((m * 3 + k) * 320 + dd_)) * 256 + ot * 64 + oq_);
      for (int dt = 0; dt < 320; dt += 16) {
        Wst[dd_][oq_ + 0] = pref.x;
        Wst[dd_][oq_ + 1] = pref.y;
        Wst[dd_][oq_ + 2] = pref.z;
        Wst[dd_][oq_ + 3] = pref.w;
        __syncthreads();
        if (dt + 16 < 320)
          pref = *(const float4*)(Wgat +
                                  ((size_t)((m * 3 + k) * 320 + dt + 16 + dd_)) * 256 + ot * 64 + oq_);
#pragma unroll
        for (int dd = 0; dd < 16; ++dd) {
          float av = adus_l[ag][dt + dd];
          const float4 w0 = *(const float4*)(&Wst[dd][og * 8]);
          const float4 w1 = *(const float4*)(&Wst[dd][og * 8 + 4]);
          acc[0] += av * w0.x; acc[1] += av * w0.y; acc[2] += av * w0.z; acc[3] += av * w0.w;
          acc[4] += av * w1.x; acc[5] += av * w1.y; acc[6] += av * w1.z; acc[7] += av * w1.w;
        }
        __syncthreads();
      }
#pragma unroll
      for (int i = 0; i < 8; ++i) hp_t[ag][og * 8 + i] = acc[i];
      __syncthreads();
      float oacc[8];
#pragma unroll
      for (int i = 0; i < 8; ++i) oacc[i] = 0.f;
      for (int e = 0; e < 48; ++e) {
        if (valid_l[e] && dst_l[e] == ag) {
          float alv = alpha_l[e * 3 + k];
          int s = src_l[e];
#pragma unroll
          for (int i = 0; i < 8; ++i) oacc[i] += alv * hp_t[s][og * 8 + i];
        }
      }
#pragma unroll
      for (int i = 0; i < 8; ++i) {
        int o = ot * 64 + og * 8 + i;
        float v = eluf(oacc[i] + bgat[(m * 3 + k) * 256 + o]);
        zgat[((size_t)(c * 4 + m) * 32 + ag) * 768 + k * 256 + o] = v;
      }
      __syncthreads();
    }
  }
}

// ---------- K3w: semantic attention ----------
__global__ __launch_bounds__(256) void k_sem(const float* __restrict__ zgat,
                                             const float* __restrict__ Wsem,
                                             const float* __restrict__ bsem,
                                             const float* __restrict__ qsem,
                                             const void* __restrict__ amask,
                                             float* __restrict__ wsem) {
  __shared__ float Wst[64][128];
  __shared__ float zl[32][64];
  __shared__ float wred[256];
  __shared__ float war[32];
  const int c = blockIdx.x >> 2, m = blockIdx.x & 3;
  const int tid = threadIdx.x;
  const int mb = maskmode(amask);
  const int a = tid >> 3, hg = tid & 7;
  float acc[16];
#pragma unroll
  for (int i = 0; i < 16; ++i) acc[i] = 0.f;
  const float* zbase = zgat + (size_t)(c * 4 + m) * 32 * 768;
  for (int jt = 0; jt < 768; jt += 64) {
    for (int l = 0; l < 8; ++l) {
      int f4 = l * 256 + tid;
      int row = f4 >> 5, c4 = (f4 & 31) * 4;
      *(float4*)&Wst[row][c4] = *(const float4*)(Wsem + (size_t)(jt + row) * 128 + c4);
    }
    for (int l = 0; l < 2; ++l) {
      int f4 = l * 256 + tid;
      int row = f4 >> 4, c4 = (f4 & 15) * 4;
      *(float4*)&zl[row][c4] = *(const float4*)(zbase + (size_t)row * 768 + jt + c4);
    }
    __syncthreads();
    for (int j = 0; j < 64; ++j) {
      float zv = zl[a][j];
      const float* wp = &Wst[j][hg * 16];
#pragma unroll
      for (int i = 0; i < 16; ++i) acc[i] += zv * wp[i];
    }
    __syncthreads();
  }
  float wp_ = 0.f;
#pragma unroll
  for (int i = 0; i < 16; ++i) {
    int h = hg * 16 + i;
    wp_ += tanhf_fast(acc[i] + bsem[h]) * qsem[h];
  }
  wred[tid] = wp_;
  __syncthreads();
  if (tid < 32) {
    float s = 0.f;
    for (int q = 0; q < 8; ++q) s += wred[tid * 8 + q];
    war[tid] = s;
  }
  __syncthreads();
  if (tid == 0) {
    float s = 0.f;
    int cnt = 0;
    for (int aa = 0; aa < 32; ++aa)
      if (ldmask(amask, c * 32 + aa, mb)) { s += war[aa]; cnt++; }
    wsem[c * 4 + m] = s / (float)(cnt > 1 ? cnt : 1);
  }
}

// ---------- K3b: per-comment assembly. Weights staged in LDS (wbuf 53KB). ----------
__global__ __launch_bounds__(256) void k_comment(
    const float* __restrict__ zgat, const float* __restrict__ wsem,
    const float* __restrict__ cemb_ws, const float* __restrict__ Wpred,
    const float* __restrict__ bpred, const float* __restrict__ Wadu1,
    const float* __restrict__ badu1, const float* __restrict__ Wadu2,
    const float* __restrict__ badu2, const float* __restrict__ Winn1,
    const float* __restrict__ binn1, const float* __restrict__ Winn2,
    const float* __restrict__ binn2, const float* __restrict__ Wint1,
    const float* __restrict__ bint1, const float* __restrict__ Wint2,
    const float* __restrict__ bint2, const float* __restrict__ info,
    const void* __restrict__ amask, const void* __restrict__ lmask,
    const int* __restrict__ isrc, const int* __restrict__ idst,
    const int* __restrict__ irel, const void* __restrict__ imask, const int* __restrict__ tsrc,
    const int* __restrict__ tdst, const int* __restrict__ trel, const void* __restrict__ tmask,
    float* __restrict__ woctx, float* __restrict__ dout) {
  __shared__ float zf[32][133];
  __shared__ float ae[32][257];
  __shared__ float wbuf[13344];
  __shared__ float cemb_l[320];
  __shared__ float beta_l[4];
  __shared__ float pred_l[48][16];
  __shared__ float sE[48], alE[48];
  __shared__ int seL[48], deL[48], relL[48], mskL[48];
  __shared__ float wredA[256];
  __shared__ float sA[32], alA[32];
  __shared__ int mskA[32];
  const int c = blockIdx.x, tid = threadIdx.x;
  const int mb = maskmode(amask);

  if (tid == 0) {
    float w0 = wsem[c * 4], w1 = wsem[c * 4 + 1], w2 = wsem[c * 4 + 2], w3 = wsem[c * 4 + 3];
    float mx = fmaxf(fmaxf(w0, w1), fmaxf(w2, w3));
    float e0 = __expf(w0 - mx), e1 = __expf(w1 - mx), e2 = __expf(w2 - mx), e3 = __expf(w3 - mx);
    float s = e0 + e1 + e2 + e3;
    beta_l[0] = e0 / s; beta_l[1] = e1 / s; beta_l[2] = e2 / s; beta_l[3] = e3 / s;
  }
  for (int d = tid; d < 320; d += 256) cemb_l[d] = cemb_ws[c * 320 + d];
  __syncthreads();

  const int ag = tid >> 5;
  const int og = tid & 31;
  float acc[4][8];
#pragma unroll
  for (int i = 0; i < 4; ++i)
#pragma unroll
    for (int j = 0; j < 8; ++j) acc[i][j] = 0.f;
  const float b0 = beta_l[0], b1 = beta_l[1], b2 = beta_l[2], b3 = beta_l[3];
  const float* zc0 = zgat + (size_t)(c * 4 + 0) * 32 * 768;
  const float* zc1 = zgat + (size_t)(c * 4 + 1) * 32 * 768;
  const float* zc2 = zgat + (size_t)(c * 4 + 2) * 32 * 768;
  const float* zc3 = zgat + (size_t)(c * 4 + 3) * 32 * 768;
  for (int jt = 0; jt < 768; jt += 128) {
    for (int l = 0; l < 16; ++l) {
      int idx = l * 256 + tid;
      int a = idx >> 7, j = idx & 127;
      size_t off = (size_t)a * 768 + jt + j;
      zf[a][j] = b0 * zc0[off] + b1 * zc1[off] + b2 * zc2[off] + b3 * zc3[off];
    }
    __syncthreads();
    const float* wp0 = Wpred + (size_t)jt * 256 + og * 8;
    float4 w0v = *(const float4*)wp0;
    float4 w1v = *(const float4*)(wp0 + 4);
    for (int j = 0; j < 128; ++j) {
      float4 n0v, n1v;
      if (j + 1 < 128) {
        const float* wp = Wpred + (size_t)(jt + j + 1) * 256 + og * 8;
        n0v = *(const float4*)wp;
        n1v = *(const float4*)(wp + 4);
      }
      float w8[8] = {w0v.x, w0v.y, w0v.z, w0v.w, w1v.x, w1v.y, w1v.z, w1v.w};
      float z0 = zf[ag * 4 + 0][j], z1 = zf[ag * 4 + 1][j];
      float z2 = zf[ag * 4 + 2][j], z3 = zf[ag * 4 + 3][j];
#pragma unroll
      for (int jj = 0; jj < 8; ++jj) {
        acc[0][jj] += z0 * w8[jj];
        acc[1][jj] += z1 * w8[jj];
        acc[2][jj] += z2 * w8[jj];
        acc[3][jj] += z3 * w8[jj];
      }
      if (j + 1 < 128) { w0v = n0v; w1v = n1v; }
    }
    __syncthreads();
  }
#pragma unroll
  for (int i = 0; i < 4; ++i)
#pragma unroll
    for (int jj = 0; jj < 8; ++jj)
      ae[ag * 4 + i][og * 8 + jj] = acc[i][jj] + bpred[og * 8 + jj];
  for (int idx = tid; idx < 9216; idx += 256) wbuf[idx] = Wadu1[idx];
  __syncthreads();

  {
    const int a = tid >> 3, hg = tid & 7;
    float sacc = 0.f;
    for (int hh = 0; hh < 2; ++hh) {
      int h = hg * 2 + hh;
      float d = badu1[h];
      for (int dd = 0; dd < 320; ++dd) d += cemb_l[dd] * wbuf[dd * 16 + h];
      for (int dd = 0; dd < 256; ++dd) d += ae[a][dd] * wbuf[(320 + dd) * 16 + h];
      sacc += fmaxf(d, 0.f) * Wadu2[h];
    }
    wredA[tid] = sacc;
  }
  __syncthreads();
  if (tid < 32) {
    float s = badu2[0];
    for (int q = 0; q < 8; ++q) s += wredA[tid * 8 + q];
    sA[tid] = s;
    mskA[tid] = (ldmask(amask, c * 32 + tid, mb) != 0) && (ldmask(lmask, c * 32 + tid, mb) != 0);
  }
  __syncthreads();
  if (tid == 0) {
    float mx = -1e30f;
    int any = 0;
    for (int a = 0; a < 32; ++a)
      if (mskA[a]) { any = 1; mx = fmaxf(mx, sA[a]); }
    float s = 0.f;
    for (int a = 0; a < 32; ++a) {
      float v = mskA[a] ? __expf(sA[a] - mx) : 0.f;
      alA[a] = v;
      s += v;
    }
    if (any)
      for (int a = 0; a < 32; ++a) alA[a] /= s;
  }
  __syncthreads();
  {
    int o = tid;
    float v = 0.f;
    for (int a = 0; a < 32; ++a) v += alA[a] * ae[a][o];
    woctx[c * 1608 + o] = v;
    dout[(size_t)c * 1808 + 200 + o] = v;
  }
  __syncthreads();

  for (int pp = 0; pp < 2; ++pp) {
    const float *W1, *b1v, *W2, *b2v;
    const int *seP, *deP, *relP;
    const void* mskP;
    int outoff;
    if (pp == 0) {
      W1 = Winn1; b1v = binn1; W2 = Winn2; b2v = binn2;
      seP = isrc; deP = idst; relP = irel; mskP = imask; outoff = 256;
    } else {
      W1 = Wint1; b1v = bint1; W2 = Wint2; b2v = bint2;
      seP = tdst; deP = tsrc; relP = trel; mskP = tmask; outoff = 770;
    }
    if (tid < 48) {
      seL[tid] = seP[c * 48 + tid];
      deL[tid] = deP[c * 48 + tid];
      relL[tid] = relP[c * 48 + tid];
      mskL[tid] = (ldmask(mskP, c * 48 + tid, mb) != 0);
    }
    for (int idx = tid; idx < 13344; idx += 256) wbuf[idx] = W1[idx];
    __syncthreads();
    for (int u = tid; u < 768; u += 256) {
      int e = u >> 4, h = u & 15;
      int se = seL[e], de = deL[e];
      float rel = (float)relL[e];
      float d = b1v[h];
      for (int dd = 0; dd < 320; ++dd) d += cemb_l[dd] * wbuf[dd * 16 + h];
      for (int dd = 0; dd < 256; ++dd) d += ae[se][dd] * wbuf[(320 + dd) * 16 + h];
      for (int dd = 0; dd < 256; ++dd) d += ae[de][dd] * wbuf[(576 + dd) * 16 + h];
      d += rel * wbuf[832 * 16 + h] + (1.f - rel) * wbuf[833 * 16 + h];
      pred_l[e][h] = fmaxf(d, 0.f) * W2[h];
    }
    __syncthreads();
    if (tid < 48) {
      float s = b2v[0];
      for (int h = 0; h < 16; ++h) s += pred_l[tid][h];
      sE[tid] = s;
    }
    __syncthreads();
    if (tid == 0) {
      float mx = -1e30f;
      int any = 0;
      for (int e = 0; e < 48; ++e)
        if (mskL[e]) { any = 1; mx = fmaxf(mx, sE[e]); }
      float s = 0.f;
      for (int e = 0; e < 48; ++e) {
        float v = mskL[e] ? __expf(sE[e] - mx) : 0.f;
        alE[e] = v;
        s += v;
      }
      if (any)
        for (int e = 0; e < 48; ++e) alE[e] /= s;
    }
    __syncthreads();
    for (int dim = tid; dim < 514; dim += 256) {
      float v = 0.f;
      for (int e = 0; e < 48; ++e) {
        float alv = alE[e];
        float pe;
        if (dim < 256) pe = ae[seL[e]][dim];
        else if (dim < 512) pe = ae[deL[e]][dim - 256];
        else if (dim == 512) pe = (float)relL[e];
        else pe = 1.f - (float)relL[e];
        v += alv * pe;
      }
      woctx[c * 1608 + outoff + dim] = v;
      dout[(size_t)c * 1808 + 200 + outoff + dim] = v;
    }
    __syncthreads();
  }

  if (tid < 4) {
    float v = info[c * 4 + tid];
    woctx[c * 1608 + 1284 + tid] = v;
    dout[(size_t)c * 1808 + 200 + 1284 + tid] = v;
  }
  for (int d = tid; d < 320; d += 256) {
    float v = cemb_l[d];
    woctx[c * 1608 + 1288 + d] = v;
    dout[(size_t)c * 1808 + 200 + 1288 + d] = v;
  }
}

// ---------- K4a: ctx LSTM input projection ----------
__global__ __launch_bounds__(256) void k_ctx_in(const float* __restrict__ woctx,
                                                const float* __restrict__ Wihc,
                                                const float* __restrict__ bc,
                                                float* __restrict__ xc) {
  __shared__ float woc[64][133];
  __shared__ float Wst[8][128];
  const int r0 = blockIdx.x * 8;
  const int tid = threadIdx.x;
  const int t = tid & 63, rg = tid >> 6;
  float a0 = 0.f, a1 = 0.f;
  for (int d0 = 0; d0 < 1608; d0 += 128) {
    int jn = 1608 - d0;
    if (jn > 128) jn = 128;
    for (int l = 0; l < 32; ++l) {
      int idx = l * 256 + tid;
      int tt = idx >> 7, j = idx & 127;
      woc[tt][j] = (j < jn) ? woctx[(size_t)tt * 1608 + d0 + j] : 0.f;
    }
    {
      int rr = tid >> 5, jb = tid & 31;
      for (int q = 0; q < 4; ++q) {
        int jj = jb * 4 + q;
        Wst[rr][jj] = (jj < jn) ? Wihc[(size_t)(r0 + rr) * 1608 + d0 + jj] : 0.f;
      }
    }
    __syncthreads();
    for (int j = 0; j < 128; ++j) {
      float x = woc[t][j];
      a0 += x * Wst[rg * 2 + 0][j];
      a1 += x * Wst[rg * 2 + 1][j];
    }
    __syncthreads();
  }
  int r = r0 + rg * 2;
  xc[t * 800 + r] = a0 + bc[r];
  xc[t * 800 + r + 1] = a1 + bc[r + 1];
}

// ---------- K4b: ctx LSTM recurrence ----------
__global__ __launch_bounds__(832) void k_ctx_rec(const float* __restrict__ xc,
                                                 const uint4* __restrict__ wt4,
                                                 float* __restrict__ dout) {
  __shared__ alignas(16) u32 hl2[100];
  __shared__ float zc[800];
  const int tid = threadIdx.x;
  if (tid < 100) hl2[tid] = 0;
  float cst = 0.f;
  __syncthreads();
  for (int t = 0; t < 64; ++t) {
    if (tid < 800) {
      float a0 = xc[t * 800 + tid], a1 = 0.f, a2 = 0.f, a3 = 0.f;
#pragma unroll 5
      for (int k4 = 0; k4 < 25; ++k4) {
        uint4 wv = wt4[(size_t)k4 * 800 + tid];
        uint4 hq = *(const uint4*)&hl2[k4 * 4];
        a0 = dot2h(wv.x, hq.x, a0);
        a1 = dot2h(wv.y, hq.y, a1);
        a2 = dot2h(wv.z, hq.z, a2);
        a3 = dot2h(wv.w, hq.w, a3);
      }
      zc[tid] = (a0 + a1) + (a2 + a3);
    }
    __syncthreads();
    if (tid < 200) {
      float iv = sigf(zc[tid]);
      float fv = sigf(zc[200 + tid]);
      float gv = tanhf_fast(zc[400 + tid]);
      float ov = sigf(zc[600 + tid]);
      cst = fv * cst + iv * gv;
      float h = ov * tanhf_fast(cst);
      ((u16*)hl2)[tid] = __half_as_ushort(__float2half(h));
      dout[(size_t)t * 1808 + tid] = h;
    }
    __syncthreads();
  }
}

// ---------- launch ----------
extern "C" void kernel_launch(void* const* d_in, const int* in_sizes, int n_in, void* d_out,
                              int out_size, void* d_ws, size_t ws_size, hipStream_t stream) {
  const float* emb = (const float*)d_in[0];
  const float* info = (const float*)d_in[1];
  const int* cspan = (const int*)d_in[2];
  const int* aspan = (const int*)d_in[3];
  const void* amask = d_in[4];
  const void* lmask = d_in[5];
  const int* isrc = (const int*)d_in[6];
  const int* idst = (const int*)d_in[7];
  const int* irel = (const int*)d_in[8];
  const void* imask = d_in[9];
  const int* tsrc = (const int*)d_in[10];
  const int* tdst = (const int*)d_in[11];
  const int* trel = (const int*)d_in[12];
  const void* tmask = d_in[13];
  const float* Wihf = (const float*)d_in[14];
  const float* Whhf = (const float*)d_in[15];
  const float* bfv = (const float*)d_in[16];
  const float* Wihb = (const float*)d_in[17];
  const float* Whhb = (const float*)d_in[18];
  const float* bbv = (const float*)d_in[19];
  const float* Wgat = (const float*)d_in[20];
  const float* al = (const float*)d_in[21];
  const float* ar = (const float*)d_in[22];
  const float* bgat = (const float*)d_in[23];
  const float* Wsem = (const float*)d_in[24];
  const float* bsem = (const float*)d_in[25];
  const float* qsem = (const float*)d_in[26];
  const float* Wpred = (const float*)d_in[27];
  const float* bpred = (const float*)d_in[28];
  const float* Wadu1 = (const float*)d_in[29];
  const float* badu1 = (const float*)d_in[30];
  const float* Wadu2 = (const float*)d_in[31];
  const float* badu2 = (const float*)d_in[32];
  const float* Winn1 = (const float*)d_in[33];
  const float* binn1 = (const float*)d_in[34];
  const float* Winn2 = (const float*)d_in[35];
  const float* binn2 = (const float*)d_in[36];
  const float* Wint1 = (const float*)d_in[37];
  const float* bint1 = (const float*)d_in[38];
  const float* Wint2 = (const float*)d_in[39];
  const float* bint2 = (const float*)d_in[40];
  const float* Wihc = (const float*)d_in[41];
  const float* Whhc = (const float*)d_in[42];
  const float* bc = (const float*)d_in[43];
  float* out = (float*)d_out;
  float* ws = (float*)d_ws;

  const size_t OFF_Z = 0;                                    // 65536*640
  const size_t OFF_HF = OFF_Z + (size_t)65536 * 640;         // 64*1024*80
  const size_t OFF_HB = OFF_HF + (size_t)64 * 1024 * 80;
  const size_t OFF_ZG = OFF_HB + (size_t)64 * 1024 * 80;     // 64*4*32*768
  const size_t OFF_AD = OFF_ZG + (size_t)64 * 4 * 32 * 768;  // 64*32*320
  const size_t OFF_CE = OFF_AD + (size_t)64 * 32 * 320;      // 64*320
  const size_t OFF_WS4 = OFF_CE + 64 * 320;                  // 256
  const size_t OFF_ALP = OFF_WS4 + 256;                      // 3840
  const size_t OFF_ARP = OFF_ALP + 3840;                     // 3840
  const size_t OFF_WO = OFF_ARP + 3840;                      // 64*1608
  const size_t OFF_XC = OFF_WO + (size_t)64 * 1608;          // 64*800
  const size_t OFF_WT = OFF_XC + (size_t)64 * 800;           // 80000 u32
  const size_t TOTAL = OFF_WT + 80000;

  if (n_in < 44 || ws_size < TOTAL * sizeof(float)) {
    k_marker<<<1, 1, 0, stream>>>(out);
    return;
  }

  k_prep<<<960, 256, 0, stream>>>(Wgat, al, ar, ws + OFF_ALP, ws + OFF_ARP);
  k_pack<<<79, 256, 0, stream>>>(Whhc, (uint4*)(ws + OFF_WT));
  dim3 g1(5, 512);  // n-tiles fastest: 5 consecutive blocks reuse one A-panel
  k_gemm_in<<<g1, 256, 0, stream>>>(emb, Wihf, Wihb, bfv, bbv, ws + OFF_Z);
  k_lstm_tok<<<128, 320, 0, stream>>>(ws + OFF_Z, Whhf, Whhb, ws + OFF_HF, ws + OFF_HB);
  k_span<<<64, 256, 0, stream>>>(ws + OFF_HF, ws + OFF_HB, cspan, aspan, amask, ws + OFF_AD,
                                 ws + OFF_CE);
  k_gat<<<256, 256, 0, stream>>>(ws + OFF_AD, ws + OFF_ALP, ws + OFF_ARP, Wgat, bgat, isrc, idst,
                                 irel, imask, tsrc, tdst, trel, tmask, amask, ws + OFF_ZG);
  k_sem<<<256, 256, 0, stream>>>(ws + OFF_ZG, Wsem, bsem, qsem, amask, ws + OFF_WS4);
  k_comment<<<64, 256, 0, stream>>>(ws + OFF_ZG, ws + OFF_WS4, ws + OFF_CE, Wpred, bpred, Wadu1,
                                    badu1, Wadu2, badu2, Winn1, binn1, Winn2, binn2, Wint1, bint1,
                                    Wint2, bint2, info, amask, lmask, isrc, idst, irel, imask,
                                    tsrc, tdst, trel, tmask, ws + OFF_WO, out);
  k_ctx_in<<<100, 256, 0, stream>>>(ws + OFF_WO, Wihc, bc, ws + OFF_XC);
  k_ctx_rec<<<1, 832, 0, stream>>>(ws + OFF_XC, (const uint4*)(ws + OFF_WT), out);
}

// Round 16
// 1656.656 us; speedup vs baseline: 1.1128x; 1.0160x over previous
//
#include <hip/hip_runtime.h>
#include <hip/hip_bf16.h>
#include <hip/hip_fp16.h>
#include <stdint.h>

typedef unsigned int u32;
typedef unsigned short u16;
typedef __attribute__((ext_vector_type(8))) short short8;
typedef __attribute__((ext_vector_type(4))) float f32x4;
typedef _Float16 half2v __attribute__((ext_vector_type(2)));

#if defined(__has_builtin)
#if __has_builtin(__builtin_amdgcn_fdot2)
#define HAVE_FDOT2 1
#endif
#endif

// ---------- helpers ----------
__device__ __forceinline__ float bf2f_u(u32 lo16) { return __uint_as_float(lo16 << 16); }
__device__ __forceinline__ u32 f2bf_bits(float x) {
  u32 u = __float_as_uint(x);
  return (u + 0x7fffu + ((u >> 16) & 1u)) >> 16;
}
__device__ __forceinline__ u32 pk2bf_tr(float x, float y) {  // truncating pack, 2 VALU
  return (__float_as_uint(y) & 0xffff0000u) | (__float_as_uint(x) >> 16);
}
__device__ __forceinline__ u32 pkh(float x, float y) {  // two f16 in a u32
  return (u32)__half_as_ushort(__float2half(x)) |
         ((u32)__half_as_ushort(__float2half(y)) << 16);
}
__device__ __forceinline__ float dot2h(u32 w, u32 h, float acc) {
#ifdef HAVE_FDOT2
  return __builtin_amdgcn_fdot2(__builtin_bit_cast(half2v, w), __builtin_bit_cast(half2v, h),
                                acc, false);
#else
  union { u32 u; __half2 h2; } uw, uh;
  uw.u = w; uh.u = h;
  float2 wf = __half22float2(uw.h2);
  float2 hf = __half22float2(uh.h2);
  return acc + wf.x * hf.x + wf.y * hf.y;
#endif
}
__device__ __forceinline__ float sigf(float x) { return 1.0f / (1.0f + __expf(-x)); }
__device__ __forceinline__ float tanhf_fast(float x) {
  float ax = fabsf(x);
  float e = __expf(-2.0f * ax);
  float t = (1.0f - e) / (1.0f + e);
  return x < 0.0f ? -t : t;
}
__device__ __forceinline__ float eluf(float x) { return x > 0.0f ? x : __expf(x) - 1.0f; }
__device__ __forceinline__ float lreluf(float x) { return x > 0.0f ? x : 0.2f * x; }

__device__ __forceinline__ int maskmode(const void* am) { return (*(const u32*)am) > 0xFFu; }
__device__ __forceinline__ int ldmask(const void* p, int i, int mb) {
  return mb ? (int)((const unsigned char*)p)[i] : ((const int*)p)[i];
}

__global__ void k_marker(float* out) { out[0] = 12345.0f; }

// ---------- K0: precompute W_gat @ a_l / a_r (wave-per-output, coalesced) ----------
__global__ __launch_bounds__(256) void k_prep(const float* __restrict__ Wgat,
                                              const float* __restrict__ al,
                                              const float* __restrict__ ar,
                                              float* __restrict__ alproj,
                                              float* __restrict__ arproj) {
  int w = blockIdx.x * 4 + (threadIdx.x >> 6);
  int lane = threadIdx.x & 63;
  if (w >= 3840) return;
  int mk = w / 320, d = w % 320;
  const float* wrow = Wgat + ((size_t)mk * 320 + d) * 256;
  const float* alp = al + mk * 256;
  const float* arp = ar + mk * 256;
  float sa = 0.f, sb = 0.f;
#pragma unroll
  for (int q = 0; q < 4; ++q) {
    int o = lane + q * 64;
    float wv = wrow[o];
    sa += wv * alp[o];
    sb += wv * arp[o];
  }
#pragma unroll
  for (int off = 32; off; off >>= 1) {
    sa += __shfl_down(sa, off, 64);
    sb += __shfl_down(sb, off, 64);
  }
  if (lane == 0) { alproj[w] = sa; arproj[w] = sb; }
}

// ---------- K0b: Whh_c -> wt4[k4][800] uint4 of f16 pairs ----------
__global__ void k_pack(const float* __restrict__ whhc, uint4* __restrict__ wt4) {
  int idx = blockIdx.x * 256 + threadIdx.x;
  if (idx >= 20000) return;
  int k4 = idx / 800, r = idx % 800;
  const float* p = whhc + r * 200 + k4 * 8;
  wt4[idx] = (uint4){pkh(p[0], p[1]), pkh(p[2], p[3]), pkh(p[4], p[5]), pkh(p[6], p[7])};
}

// ---------- K1: input GEMM (MFMA bf16), trunc pack-in-loop, plain Z[m][640] ----------
__global__ __launch_bounds__(256) void k_gemm_in(
    const float* __restrict__ emb, const float* __restrict__ Wf, const float* __restrict__ Wb,
    const float* __restrict__ biasf, const float* __restrict__ biasb, float* __restrict__ Z) {
  __shared__ u16 Albs[128 * 40];
  __shared__ u16 Blbs[128 * 40];
  __shared__ float bias_l[128];
  const int tid = threadIdx.x;
  const int n0 = blockIdx.x * 128;
  const int m0 = blockIdx.y * 128;

  if (tid < 128) {
    int ng = n0 + tid;
    bias_l[tid] = (ng < 320) ? biasf[ng] : biasb[ng - 320];
  }
  const int srow = tid >> 1, shalf = tid & 1;
  const float* asrc = emb + (size_t)(m0 + srow) * 768 + shalf * 16;
  const int ngb = n0 + srow;
  const float* bsrc =
      ((ngb < 320) ? (Wf + (size_t)ngb * 768) : (Wb + (size_t)(ngb - 320) * 768)) + shalf * 16;
  u32* aw = (u32*)&Albs[srow * 40 + shalf * 16];
  u32* bw = (u32*)&Blbs[srow * 40 + shalf * 16];

  const int lane = tid & 63;
  const int lr = lane & 15, sub = lane >> 4;
  const int wv = tid >> 6, wm = wv >> 1, wn = wv & 1;
  const u16* abase = &Albs[(wm * 64 + lr) * 40 + sub * 8];
  const u16* bbase = &Blbs[(wn * 64 + lr) * 40 + sub * 8];

  f32x4 acc[4][4];
#pragma unroll
  for (int i = 0; i < 4; ++i)
#pragma unroll
    for (int j = 0; j < 4; ++j) acc[i][j] = (f32x4)(0.f);

  float4 a0, a1, a2, a3, b0, b1, b2, b3;
  u32 pra[8], prb[8];
  a0 = *(const float4*)(asrc + 0); a1 = *(const float4*)(asrc + 4);
  a2 = *(const float4*)(asrc + 8); a3 = *(const float4*)(asrc + 12);
  b0 = *(const float4*)(bsrc + 0); b1 = *(const float4*)(bsrc + 4);
  b2 = *(const float4*)(bsrc + 8); b3 = *(const float4*)(bsrc + 12);
  pra[0] = pk2bf_tr(a0.x, a0.y); pra[1] = pk2bf_tr(a0.z, a0.w);
  pra[2] = pk2bf_tr(a1.x, a1.y); pra[3] = pk2bf_tr(a1.z, a1.w);
  pra[4] = pk2bf_tr(a2.x, a2.y); pra[5] = pk2bf_tr(a2.z, a2.w);
  pra[6] = pk2bf_tr(a3.x, a3.y); pra[7] = pk2bf_tr(a3.z, a3.w);
  prb[0] = pk2bf_tr(b0.x, b0.y); prb[1] = pk2bf_tr(b0.z, b0.w);
  prb[2] = pk2bf_tr(b1.x, b1.y); prb[3] = pk2bf_tr(b1.z, b1.w);
  prb[4] = pk2bf_tr(b2.x, b2.y); prb[5] = pk2bf_tr(b2.z, b2.w);
  prb[6] = pk2bf_tr(b3.x, b3.y); prb[7] = pk2bf_tr(b3.z, b3.w);

  for (int it = 0; it < 24; ++it) {
    __syncthreads();
#pragma unroll
    for (int q = 0; q < 8; ++q) { aw[q] = pra[q]; bw[q] = prb[q]; }
    __syncthreads();
    const bool more = (it + 1 < 24);
    if (more) {
      const int k0 = (it + 1) * 32;
      a0 = *(const float4*)(asrc + k0); a1 = *(const float4*)(asrc + k0 + 4);
      a2 = *(const float4*)(asrc + k0 + 8); a3 = *(const float4*)(asrc + k0 + 12);
      b0 = *(const float4*)(bsrc + k0); b1 = *(const float4*)(bsrc + k0 + 4);
      b2 = *(const float4*)(bsrc + k0 + 8); b3 = *(const float4*)(bsrc + k0 + 12);
    }
    short8 bfr[4];
#pragma unroll
    for (int nf = 0; nf < 4; ++nf) bfr[nf] = *(const short8*)(bbase + nf * 640);
#pragma unroll
    for (int mf = 0; mf < 4; ++mf) {
      short8 af = *(const short8*)(abase + mf * 640);
#pragma unroll
      for (int nf = 0; nf < 4; ++nf)
        acc[mf][nf] = __builtin_amdgcn_mfma_f32_16x16x32_bf16(af, bfr[nf], acc[mf][nf], 0, 0, 0);
    }
    if (more) {
      pra[0] = pk2bf_tr(a0.x, a0.y); pra[1] = pk2bf_tr(a0.z, a0.w);
      pra[2] = pk2bf_tr(a1.x, a1.y); pra[3] = pk2bf_tr(a1.z, a1.w);
      pra[4] = pk2bf_tr(a2.x, a2.y); pra[5] = pk2bf_tr(a2.z, a2.w);
      pra[6] = pk2bf_tr(a3.x, a3.y); pra[7] = pk2bf_tr(a3.z, a3.w);
      prb[0] = pk2bf_tr(b0.x, b0.y); prb[1] = pk2bf_tr(b0.z, b0.w);
      prb[2] = pk2bf_tr(b1.x, b1.y); prb[3] = pk2bf_tr(b1.z, b1.w);
      prb[4] = pk2bf_tr(b2.x, b2.y); prb[5] = pk2bf_tr(b2.z, b2.w);
      prb[6] = pk2bf_tr(b3.x, b3.y); prb[7] = pk2bf_tr(b3.z, b3.w);
    }
  }
#pragma unroll
  for (int mf = 0; mf < 4; ++mf) {
#pragma unroll
    for (int nf = 0; nf < 4; ++nf) {
      int col = wn * 64 + nf * 16 + lr;
      float bias = bias_l[col];
      size_t mrow = (size_t)m0 + wm * 64 + mf * 16 + sub * 4;
#pragma unroll
      for (int j = 0; j < 4; ++j)
        Z[(mrow + j) * 640 + n0 + col] = acc[mf][nf][j] + bias;
    }
  }
}

// ---------- K2: token LSTM (round-12 structure + gate-activation hoisted into the
// 320-thread matvec phase). Row j's gate is known from j (0-159,240-319: sigmoid;
// 160-239: tanh), so the producer applies it; the serial 80-thread phase keeps only
// ONE transcendental (tanh(c)) instead of five -> shorter critical path per step.
__global__ __launch_bounds__(320, 1) void k_lstm_tok(const float* __restrict__ Z,
                                                     const float* __restrict__ Whhf,
                                                     const float* __restrict__ Whhb,
                                                     float* __restrict__ hf,
                                                     float* __restrict__ hb) {
  __shared__ uint2 wq[20 * 320];
  __shared__ alignas(16) u32 hpk[40];
  __shared__ float zbuf[320];
  const int tid = threadIdx.x;
  const int c = blockIdx.x >> 1;
  const int dir = blockIdx.x & 1;
  const float* Whh = dir ? Whhb : Whhf;
  float* hout = dir ? hb : hf;

  for (int idx = tid; idx < 20 * 320; idx += 320) {
    int k4 = idx / 320, r = idx % 320;
    const float* p = Whh + (size_t)r * 80 + k4 * 4;
    wq[idx] = (uint2){pkh(p[0], p[1]), pkh(p[2], p[3])};
  }
  if (tid < 40) hpk[tid] = 0;
  __syncthreads();

  const int j = tid;
  const bool isG = (j >= 160) && (j < 240);  // g-gate rows get tanh; others sigmoid
  const uint2* wcol = wq + j;
  uint2 wv0 = wcol[0], wv1 = wcol[320], wv2 = wcol[640], wv3 = wcol[960];
  uint2 wv4 = wcol[1280], wv5 = wcol[1600], wv6 = wcol[1920], wv7 = wcol[2240];
  uint2 wv8 = wcol[2560], wv9 = wcol[2880], wv10 = wcol[3200], wv11 = wcol[3520];
  uint2 wv12 = wcol[3840], wv13 = wcol[4160], wv14 = wcol[4480], wv15 = wcol[4800];
  uint2 wv16 = wcol[5120], wv17 = wcol[5440], wv18 = wcol[5760], wv19 = wcol[6080];

  const int sgn = dir ? -1 : 1;
  const int t0 = dir ? 1023 : 0;
  const float* zb = Z + (size_t)c * 1024 * 640 + dir * 320 + j;
  float zc = zb[(size_t)t0 * 640];
  float zn = zb[(size_t)(t0 + sgn) * 640];
  float cst = 0.f;

  for (int t = 0; t < 1024; ++t) {
    const int tt = t0 + sgn * t;
    float zp = 0.f;
    if (t + 2 < 1024) zp = zb[(size_t)(t0 + sgn * (t + 2)) * 640];
    float a0 = zc, a1 = 0.f, a2 = 0.f, a3 = 0.f;
    {
      uint4 h0 = *(const uint4*)&hpk[0];
      a0 = dot2h(wv0.x, h0.x, a0); a1 = dot2h(wv0.y, h0.y, a1);
      a2 = dot2h(wv1.x, h0.z, a2); a3 = dot2h(wv1.y, h0.w, a3);
      uint4 h1 = *(const uint4*)&hpk[4];
      a0 = dot2h(wv2.x, h1.x, a0); a1 = dot2h(wv2.y, h1.y, a1);
      a2 = dot2h(wv3.x, h1.z, a2); a3 = dot2h(wv3.y, h1.w, a3);
      uint4 h2 = *(const uint4*)&hpk[8];
      a0 = dot2h(wv4.x, h2.x, a0); a1 = dot2h(wv4.y, h2.y, a1);
      a2 = dot2h(wv5.x, h2.z, a2); a3 = dot2h(wv5.y, h2.w, a3);
      uint4 h3 = *(const uint4*)&hpk[12];
      a0 = dot2h(wv6.x, h3.x, a0); a1 = dot2h(wv6.y, h3.y, a1);
      a2 = dot2h(wv7.x, h3.z, a2); a3 = dot2h(wv7.y, h3.w, a3);
      uint4 h4 = *(const uint4*)&hpk[16];
      a0 = dot2h(wv8.x, h4.x, a0); a1 = dot2h(wv8.y, h4.y, a1);
      a2 = dot2h(wv9.x, h4.z, a2); a3 = dot2h(wv9.y, h4.w, a3);
      uint4 h5 = *(const uint4*)&hpk[20];
      a0 = dot2h(wv10.x, h5.x, a0); a1 = dot2h(wv10.y, h5.y, a1);
      a2 = dot2h(wv11.x, h5.z, a2); a3 = dot2h(wv11.y, h5.w, a3);
      uint4 h6 = *(const uint4*)&hpk[24];
      a0 = dot2h(wv12.x, h6.x, a0); a1 = dot2h(wv12.y, h6.y, a1);
      a2 = dot2h(wv13.x, h6.z, a2); a3 = dot2h(wv13.y, h6.w, a3);
      uint4 h7 = *(const uint4*)&hpk[28];
      a0 = dot2h(wv14.x, h7.x, a0); a1 = dot2h(wv14.y, h7.y, a1);
      a2 = dot2h(wv15.x, h7.z, a2); a3 = dot2h(wv15.y, h7.w, a3);
      uint4 h8 = *(const uint4*)&hpk[32];
      a0 = dot2h(wv16.x, h8.x, a0); a1 = dot2h(wv16.y, h8.y, a1);
      a2 = dot2h(wv17.x, h8.z, a2); a3 = dot2h(wv17.y, h8.w, a3);
      uint4 h9 = *(const uint4*)&hpk[36];
      a0 = dot2h(wv18.x, h9.x, a0); a1 = dot2h(wv18.y, h9.y, a1);
      a2 = dot2h(wv19.x, h9.z, a2); a3 = dot2h(wv19.y, h9.w, a3);
    }
    float zr = (a0 + a1) + (a2 + a3);
    zbuf[j] = isG ? tanhf_fast(zr) : sigf(zr);  // activation hoisted to producer
    __syncthreads();
    if (j < 80) {
      float iv = zbuf[j];
      float fv = zbuf[80 + j];
      float gv = zbuf[160 + j];
      float ov = zbuf[240 + j];
      cst = fv * cst + iv * gv;
      float h = ov * tanhf_fast(cst);
      ((u16*)hpk)[j] = (u16)__half_as_ushort(__float2half(h));
      hout[((size_t)c * 1024 + tt) * 80 + j] = h;
    }
    zc = zn; zn = zp;
    __syncthreads();
  }
}

// ---------- span representation ----------
__device__ __forceinline__ float span_val(const float* __restrict__ hf,
                                          const float* __restrict__ hb, int c, int i, int j,
                                          int d) {
  size_t base = (size_t)c * 1024 * 80;
  if (d < 80) return hf[base + (size_t)j * 80 + d] - hf[base + (size_t)(i - 1) * 80 + d];
  if (d < 160) return hb[base + (size_t)i * 80 + (d - 80)] - hb[base + (size_t)(j + 1) * 80 + (d - 80)];
  if (d < 240) return hf[base + (size_t)(i - 1) * 80 + (d - 160)];
  return hb[base + (size_t)(j + 1) * 80 + (d - 240)];
}

__global__ __launch_bounds__(256) void k_span(const float* __restrict__ hf,
                                              const float* __restrict__ hb,
                                              const int* __restrict__ cspan,
                                              const int* __restrict__ aspan,
                                              const void* __restrict__ amask,
                                              float* __restrict__ adus, float* __restrict__ cembo) {
  const int c = blockIdx.x, tid = threadIdx.x;
  const int mb = maskmode(amask);
  int ci = cspan[c * 2], cj = cspan[c * 2 + 1];
  for (int d = tid; d < 320; d += 256) cembo[c * 320 + d] = span_val(hf, hb, c, ci, cj, d);
  for (int idx = tid; idx < 32 * 320; idx += 256) {
    int a = idx / 320, d = idx % 320;
    float v = 0.f;
    if (ldmask(amask, c * 32 + a, mb)) {
      int ai = aspan[(c * 32 + a) * 2], aj = aspan[(c * 32 + a) * 2 + 1];
      v = span_val(hf, hb, c, ai, aj, d);
    }
    adus[(size_t)c * 10240 + idx] = v;
  }
}

// ---------- K3a: GAT per (comment, metapath); Wst tile prefetch ----------
__global__ __launch_bounds__(256) void k_gat(
    const float* __restrict__ adus_ws, const float* __restrict__ alproj,
    const float* __restrict__ arproj, const float* __restrict__ Wgat,
    const float* __restrict__ bgat, const int* __restrict__ isrc, const int* __restrict__ idst,
    const int* __restrict__ irel, const void* __restrict__ imask, const int* __restrict__ tsrc,
    const int* __restrict__ tdst, const int* __restrict__ trel, const void* __restrict__ tmask,
    const void* __restrict__ amdet, float* __restrict__ zgat) {
  __shared__ float adus_l[32][321];
  __shared__ float Wst[16][64];
  __shared__ float hp_t[32][66];
  __shared__ float sl_l[96], sr_l[96];
  __shared__ float e_l[144], alpha_l[144], mx_l[96], den_l[96];
  __shared__ int src_l[48], dst_l[48], valid_l[48];
  const int c = blockIdx.x >> 2, m = blockIdx.x & 3;
  const int tid = threadIdx.x;
  const int mb = maskmode(amdet);

  if (tid < 48) {
    int e = tid, s, d, r, mk;
    if (m < 2) {
      s = isrc[c * 48 + e]; d = idst[c * 48 + e]; r = irel[c * 48 + e];
      mk = ldmask(imask, c * 48 + e, mb);
    } else {
      s = tdst[c * 48 + e]; d = tsrc[c * 48 + e]; r = trel[c * 48 + e];
      mk = ldmask(tmask, c * 48 + e, mb);
    }
    src_l[e] = s; dst_l[e] = d; valid_l[e] = (mk != 0) && (r == (m & 1));
  }
  for (int idx = tid; idx < 32 * 320; idx += 256)
    adus_l[idx / 320][idx % 320] = adus_ws[(size_t)c * 10240 + idx];
  __syncthreads();

  if (tid < 96) {
    int a = tid & 31, k = tid >> 5;
    const float* alp = alproj + (m * 3 + k) * 320;
    const float* arp = arproj + (m * 3 + k) * 320;
    float sa = 0.f, sb = 0.f;
    for (int d = 0; d < 320; ++d) {
      float v = adus_l[a][d];
      sa += v * alp[d];
      sb += v * arp[d];
    }
    sl_l[a * 3 + k] = sa;
    sr_l[a * 3 + k] = sb;
  }
  __syncthreads();
  if (tid < 144) {
    int e = tid % 48, k = tid / 48;
    float v = -1e30f;
    if (valid_l[e]) v = lreluf(sl_l[src_l[e] * 3 + k] + sr_l[dst_l[e] * 3 + k]);
    e_l[e * 3 + k] = v;
  }
  __syncthreads();
  if (tid < 96) {
    int a = tid & 31, k = tid >> 5;
    float mx = -1e30f;
    for (int e = 0; e < 48; ++e)
      if (valid_l[e] && dst_l[e] == a) mx = fmaxf(mx, e_l[e * 3 + k]);
    float den = 0.f;
    for (int e = 0; e < 48; ++e)
      if (valid_l[e] && dst_l[e] == a) den += __expf(e_l[e * 3 + k] - mx);
    mx_l[a * 3 + k] = mx;
    den_l[a * 3 + k] = den;
  }
  __syncthreads();
  if (tid < 144) {
    int e = tid % 48, k = tid / 48;
    float v = 0.f;
    if (valid_l[e]) {
      int d = dst_l[e];
      v = __expf(e_l[e * 3 + k] - mx_l[d * 3 + k]) / fmaxf(den_l[d * 3 + k], 1e-9f);
    }
    alpha_l[e * 3 + k] = v;
  }
  __syncthreads();

  const int ag = tid >> 3, og = tid & 7;
  const int dd_ = tid >> 4, oq_ = (tid & 15) * 4;
  for (int k = 0; k < 3; ++k) {
    for (int ot = 0; ot < 4; ++ot) {
      float acc[8];
#pragma unroll
      for (int i = 0; i < 8; ++i) acc[i] = 0.f;
      float4 pref = *(const float4*)(Wgat + ((size_t)((m * 3 + k) * 320 + dd_)) * 256 + ot * 64 + oq_);
      for (int dt = 0; dt < 320; dt += 16) {
        Wst[dd_][oq_ + 0] = pref.x;
        Wst[dd_][oq_ + 1] = pref.y;
        Wst[dd_][oq_ + 2] = pref.z;
        Wst[dd_][oq_ + 3] = pref.w;
        __syncthreads();
        if (dt + 16 < 320)
          pref = *(const float4*)(Wgat +
                                  ((size_t)((m * 3 + k) * 320 + dt + 16 + dd_)) * 256 + ot * 64 + oq_);
#pragma unroll
        for (int dd = 0; dd < 16; ++dd) {
          float av = adus_l[ag][dt + dd];
          const float4 w0 = *(const float4*)(&Wst[dd][og * 8]);
          const float4 w1 = *(const float4*)(&Wst[dd][og * 8 + 4]);
          acc[0] += av * w0.x; acc[1] += av * w0.y; acc[2] += av * w0.z; acc[3] += av * w0.w;
          acc[4] += av * w1.x; acc[5] += av * w1.y; acc[6] += av * w1.z; acc[7] += av * w1.w;
        }
        __syncthreads();
      }
#pragma unroll
      for (int i = 0; i < 8; ++i) hp_t[ag][og * 8 + i] = acc[i];
      __syncthreads();
      float oacc[8];
#pragma unroll
      for (int i = 0; i < 8; ++i) oacc[i] = 0.f;
      for (int e = 0; e < 48; ++e) {
        if (valid_l[e] && dst_l[e] == ag) {
          float alv = alpha_l[e * 3 + k];
          int s = src_l[e];
#pragma unroll
          for (int i = 0; i < 8; ++i) oacc[i] += alv * hp_t[s][og * 8 + i];
        }
      }
#pragma unroll
      for (int i = 0; i < 8; ++i) {
        int o = ot * 64 + og * 8 + i;
        float v = eluf(oacc[i] + bgat[(m * 3 + k) * 256 + o]);
        zgat[((size_t)(c * 4 + m) * 32 + ag) * 768 + k * 256 + o] = v;
      }
      __syncthreads();
    }
  }
}

// ---------- K3w: semantic attention ----------
__global__ __launch_bounds__(256) void k_sem(const float* __restrict__ zgat,
                                             const float* __restrict__ Wsem,
                                             const float* __restrict__ bsem,
                                             const float* __restrict__ qsem,
                                             const void* __restrict__ amask,
                                             float* __restrict__ wsem) {
  __shared__ float Wst[64][128];
  __shared__ float zl[32][64];
  __shared__ float wred[256];
  __shared__ float war[32];
  const int c = blockIdx.x >> 2, m = blockIdx.x & 3;
  const int tid = threadIdx.x;
  const int mb = maskmode(amask);
  const int a = tid >> 3, hg = tid & 7;
  float acc[16];
#pragma unroll
  for (int i = 0; i < 16; ++i) acc[i] = 0.f;
  const float* zbase = zgat + (size_t)(c * 4 + m) * 32 * 768;
  for (int jt = 0; jt < 768; jt += 64) {
    for (int l = 0; l < 8; ++l) {
      int f4 = l * 256 + tid;
      int row = f4 >> 5, c4 = (f4 & 31) * 4;
      *(float4*)&Wst[row][c4] = *(const float4*)(Wsem + (size_t)(jt + row) * 128 + c4);
    }
    for (int l = 0; l < 2; ++l) {
      int f4 = l * 256 + tid;
      int row = f4 >> 4, c4 = (f4 & 15) * 4;
      *(float4*)&zl[row][c4] = *(const float4*)(zbase + (size_t)row * 768 + jt + c4);
    }
    __syncthreads();
    for (int j = 0; j < 64; ++j) {
      float zv = zl[a][j];
      const float* wp = &Wst[j][hg * 16];
#pragma unroll
      for (int i = 0; i < 16; ++i) acc[i] += zv * wp[i];
    }
    __syncthreads();
  }
  float wp_ = 0.f;
#pragma unroll
  for (int i = 0; i < 16; ++i) {
    int h = hg * 16 + i;
    wp_ += tanhf_fast(acc[i] + bsem[h]) * qsem[h];
  }
  wred[tid] = wp_;
  __syncthreads();
  if (tid < 32) {
    float s = 0.f;
    for (int q = 0; q < 8; ++q) s += wred[tid * 8 + q];
    war[tid] = s;
  }
  __syncthreads();
  if (tid == 0) {
    float s = 0.f;
    int cnt = 0;
    for (int aa = 0; aa < 32; ++aa)
      if (ldmask(amask, c * 32 + aa, mb)) { s += war[aa]; cnt++; }
    wsem[c * 4 + m] = s / (float)(cnt > 1 ? cnt : 1);
  }
}

// ---------- K3b: per-comment assembly. Weights staged in LDS (wbuf 53KB). ----------
__global__ __launch_bounds__(256) void k_comment(
    const float* __restrict__ zgat, const float* __restrict__ wsem,
    const float* __restrict__ cemb_ws, const float* __restrict__ Wpred,
    const float* __restrict__ bpred, const float* __restrict__ Wadu1,
    const float* __restrict__ badu1, const float* __restrict__ Wadu2,
    const float* __restrict__ badu2, const float* __restrict__ Winn1,
    const float* __restrict__ binn1, const float* __restrict__ Winn2,
    const float* __restrict__ binn2, const float* __restrict__ Wint1,
    const float* __restrict__ bint1, const float* __restrict__ Wint2,
    const float* __restrict__ bint2, const float* __restrict__ info,
    const void* __restrict__ amask, const void* __restrict__ lmask,
    const int* __restrict__ isrc, const int* __restrict__ idst,
    const int* __restrict__ irel, const void* __restrict__ imask, const int* __restrict__ tsrc,
    const int* __restrict__ tdst, const int* __restrict__ trel, const void* __restrict__ tmask,
    float* __restrict__ woctx, float* __restrict__ dout) {
  __shared__ float zf[32][133];
  __shared__ float ae[32][257];
  __shared__ float wbuf[13344];
  __shared__ float cemb_l[320];
  __shared__ float beta_l[4];
  __shared__ float pred_l[48][16];
  __shared__ float sE[48], alE[48];
  __shared__ int seL[48], deL[48], relL[48], mskL[48];
  __shared__ float wredA[256];
  __shared__ float sA[32], alA[32];
  __shared__ int mskA[32];
  const int c = blockIdx.x, tid = threadIdx.x;
  const int mb = maskmode(amask);

  if (tid == 0) {
    float w0 = wsem[c * 4], w1 = wsem[c * 4 + 1], w2 = wsem[c * 4 + 2], w3 = wsem[c * 4 + 3];
    float mx = fmaxf(fmaxf(w0, w1), fmaxf(w2, w3));
    float e0 = __expf(w0 - mx), e1 = __expf(w1 - mx), e2 = __expf(w2 - mx), e3 = __expf(w3 - mx);
    float s = e0 + e1 + e2 + e3;
    beta_l[0] = e0 / s; beta_l[1] = e1 / s; beta_l[2] = e2 / s; beta_l[3] = e3 / s;
  }
  for (int d = tid; d < 320; d += 256) cemb_l[d] = cemb_ws[c * 320 + d];
  __syncthreads();

  const int ag = tid >> 5;
  const int og = tid & 31;
  float acc[4][8];
#pragma unroll
  for (int i = 0; i < 4; ++i)
#pragma unroll
    for (int j = 0; j < 8; ++j) acc[i][j] = 0.f;
  const float b0 = beta_l[0], b1 = beta_l[1], b2 = beta_l[2], b3 = beta_l[3];
  const float* zc0 = zgat + (size_t)(c * 4 + 0) * 32 * 768;
  const float* zc1 = zgat + (size_t)(c * 4 + 1) * 32 * 768;
  const float* zc2 = zgat + (size_t)(c * 4 + 2) * 32 * 768;
  const float* zc3 = zgat + (size_t)(c * 4 + 3) * 32 * 768;
  for (int jt = 0; jt < 768; jt += 128) {
    for (int l = 0; l < 16; ++l) {
      int idx = l * 256 + tid;
      int a = idx >> 7, j = idx & 127;
      size_t off = (size_t)a * 768 + jt + j;
      zf[a][j] = b0 * zc0[off] + b1 * zc1[off] + b2 * zc2[off] + b3 * zc3[off];
    }
    __syncthreads();
    const float* wp0 = Wpred + (size_t)jt * 256 + og * 8;
    float4 w0v = *(const float4*)wp0;
    float4 w1v = *(const float4*)(wp0 + 4);
    for (int j = 0; j < 128; ++j) {
      float4 n0v, n1v;
      if (j + 1 < 128) {
        const float* wp = Wpred + (size_t)(jt + j + 1) * 256 + og * 8;
        n0v = *(const float4*)wp;
        n1v = *(const float4*)(wp + 4);
      }
      float w8[8] = {w0v.x, w0v.y, w0v.z, w0v.w, w1v.x, w1v.y, w1v.z, w1v.w};
      float z0 = zf[ag * 4 + 0][j], z1 = zf[ag * 4 + 1][j];
      float z2 = zf[ag * 4 + 2][j], z3 = zf[ag * 4 + 3][j];
#pragma unroll
      for (int jj = 0; jj < 8; ++jj) {
        acc[0][jj] += z0 * w8[jj];
        acc[1][jj] += z1 * w8[jj];
        acc[2][jj] += z2 * w8[jj];
        acc[3][jj] += z3 * w8[jj];
      }
      if (j + 1 < 128) { w0v = n0v; w1v = n1v; }
    }
    __syncthreads();
  }
#pragma unroll
  for (int i = 0; i < 4; ++i)
#pragma unroll
    for (int jj = 0; jj < 8; ++jj)
      ae[ag * 4 + i][og * 8 + jj] = acc[i][jj] + bpred[og * 8 + jj];
  for (int idx = tid; idx < 9216; idx += 256) wbuf[idx] = Wadu1[idx];
  __syncthreads();

  {
    const int a = tid >> 3, hg = tid & 7;
    float sacc = 0.f;
    for (int hh = 0; hh < 2; ++hh) {
      int h = hg * 2 + hh;
      float d = badu1[h];
      for (int dd = 0; dd < 320; ++dd) d += cemb_l[dd] * wbuf[dd * 16 + h];
      for (int dd = 0; dd < 256; ++dd) d += ae[a][dd] * wbuf[(320 + dd) * 16 + h];
      sacc += fmaxf(d, 0.f) * Wadu2[h];
    }
    wredA[tid] = sacc;
  }
  __syncthreads();
  if (tid < 32) {
    float s = badu2[0];
    for (int q = 0; q < 8; ++q) s += wredA[tid * 8 + q];
    sA[tid] = s;
    mskA[tid] = (ldmask(amask, c * 32 + tid, mb) != 0) && (ldmask(lmask, c * 32 + tid, mb) != 0);
  }
  __syncthreads();
  if (tid == 0) {
    float mx = -1e30f;
    int any = 0;
    for (int a = 0; a < 32; ++a)
      if (mskA[a]) { any = 1; mx = fmaxf(mx, sA[a]); }
    float s = 0.f;
    for (int a = 0; a < 32; ++a) {
      float v = mskA[a] ? __expf(sA[a] - mx) : 0.f;
      alA[a] = v;
      s += v;
    }
    if (any)
      for (int a = 0; a < 32; ++a) alA[a] /= s;
  }
  __syncthreads();
  {
    int o = tid;
    float v = 0.f;
    for (int a = 0; a < 32; ++a) v += alA[a] * ae[a][o];
    woctx[c * 1608 + o] = v;
    dout[(size_t)c * 1808 + 200 + o] = v;
  }
  __syncthreads();

  for (int pp = 0; pp < 2; ++pp) {
    const float *W1, *b1v, *W2, *b2v;
    const int *seP, *deP, *relP;
    const void* mskP;
    int outoff;
    if (pp == 0) {
      W1 = Winn1; b1v = binn1; W2 = Winn2; b2v = binn2;
      seP = isrc; deP = idst; relP = irel; mskP = imask; outoff = 256;
    } else {
      W1 = Wint1; b1v = bint1; W2 = Wint2; b2v = bint2;
      seP = tdst; deP = tsrc; relP = trel; mskP = tmask; outoff = 770;
    }
    if (tid < 48) {
      seL[tid] = seP[c * 48 + tid];
      deL[tid] = deP[c * 48 + tid];
      relL[tid] = relP[c * 48 + tid];
      mskL[tid] = (ldmask(mskP, c * 48 + tid, mb) != 0);
    }
    for (int idx = tid; idx < 13344; idx += 256) wbuf[idx] = W1[idx];
    __syncthreads();
    for (int u = tid; u < 768; u += 256) {
      int e = u >> 4, h = u & 15;
      int se = seL[e], de = deL[e];
      float rel = (float)relL[e];
      float d = b1v[h];
      for (int dd = 0; dd < 320; ++dd) d += cemb_l[dd] * wbuf[dd * 16 + h];
      for (int dd = 0; dd < 256; ++dd) d += ae[se][dd] * wbuf[(320 + dd) * 16 + h];
      for (int dd = 0; dd < 256; ++dd) d += ae[de][dd] * wbuf[(576 + dd) * 16 + h];
      d += rel * wbuf[832 * 16 + h] + (1.f - rel) * wbuf[833 * 16 + h];
      pred_l[e][h] = fmaxf(d, 0.f) * W2[h];
    }
    __syncthreads();
    if (tid < 48) {
      float s = b2v[0];
      for (int h = 0; h < 16; ++h) s += pred_l[tid][h];
      sE[tid] = s;
    }
    __syncthreads();
    if (tid == 0) {
      float mx = -1e30f;
      int any = 0;
      for (int e = 0; e < 48; ++e)
        if (mskL[e]) { any = 1; mx = fmaxf(mx, sE[e]); }
      float s = 0.f;
      for (int e = 0; e < 48; ++e) {
        float v = mskL[e] ? __expf(sE[e] - mx) : 0.f;
        alE[e] = v;
        s += v;
      }
      if (any)
        for (int e = 0; e < 48; ++e) alE[e] /= s;
    }
    __syncthreads();
    for (int dim = tid; dim < 514; dim += 256) {
      float v = 0.f;
      for (int e = 0; e < 48; ++e) {
        float alv = alE[e];
        float pe;
        if (dim < 256) pe = ae[seL[e]][dim];
        else if (dim < 512) pe = ae[deL[e]][dim - 256];
        else if (dim == 512) pe = (float)relL[e];
        else pe = 1.f - (float)relL[e];
        v += alv * pe;
      }
      woctx[c * 1608 + outoff + dim] = v;
      dout[(size_t)c * 1808 + 200 + outoff + dim] = v;
    }
    __syncthreads();
  }

  if (tid < 4) {
    float v = info[c * 4 + tid];
    woctx[c * 1608 + 1284 + tid] = v;
    dout[(size_t)c * 1808 + 200 + 1284 + tid] = v;
  }
  for (int d = tid; d < 320; d += 256) {
    float v = cemb_l[d];
    woctx[c * 1608 + 1288 + d] = v;
    dout[(size_t)c * 1808 + 200 + 1288 + d] = v;
  }
}

// ---------- K4a: ctx LSTM input projection ----------
__global__ __launch_bounds__(256) void k_ctx_in(const float* __restrict__ woctx,
                                                const float* __restrict__ Wihc,
                                                const float* __restrict__ bc,
                                                float* __restrict__ xc) {
  __shared__ float woc[64][133];
  __shared__ float Wst[8][128];
  const int r0 = blockIdx.x * 8;
  const int tid = threadIdx.x;
  const int t = tid & 63, rg = tid >> 6;
  float a0 = 0.f, a1 = 0.f;
  for (int d0 = 0; d0 < 1608; d0 += 128) {
    int jn = 1608 - d0;
    if (jn > 128) jn = 128;
    for (int l = 0; l < 32; ++l) {
      int idx = l * 256 + tid;
      int tt = idx >> 7, j = idx & 127;
      woc[tt][j] = (j < jn) ? woctx[(size_t)tt * 1608 + d0 + j] : 0.f;
    }
    {
      int rr = tid >> 5, jb = tid & 31;
      for (int q = 0; q < 4; ++q) {
        int jj = jb * 4 + q;
        Wst[rr][jj] = (jj < jn) ? Wihc[(size_t)(r0 + rr) * 1608 + d0 + jj] : 0.f;
      }
    }
    __syncthreads();
    for (int j = 0; j < 128; ++j) {
      float x = woc[t][j];
      a0 += x * Wst[rg * 2 + 0][j];
      a1 += x * Wst[rg * 2 + 1][j];
    }
    __syncthreads();
  }
  int r = r0 + rg * 2;
  xc[t * 800 + r] = a0 + bc[r];
  xc[t * 800 + r + 1] = a1 + bc[r + 1];
}

// ---------- K4b: ctx LSTM recurrence ----------
__global__ __launch_bounds__(832) void k_ctx_rec(const float* __restrict__ xc,
                                                 const uint4* __restrict__ wt4,
                                                 float* __restrict__ dout) {
  __shared__ alignas(16) u32 hl2[100];
  __shared__ float zc[800];
  const int tid = threadIdx.x;
  if (tid < 100) hl2[tid] = 0;
  float cst = 0.f;
  __syncthreads();
  for (int t = 0; t < 64; ++t) {
    if (tid < 800) {
      float a0 = xc[t * 800 + tid], a1 = 0.f, a2 = 0.f, a3 = 0.f;
#pragma unroll 5
      for (int k4 = 0; k4 < 25; ++k4) {
        uint4 wv = wt4[(size_t)k4 * 800 + tid];
        uint4 hq = *(const uint4*)&hl2[k4 * 4];
        a0 = dot2h(wv.x, hq.x, a0);
        a1 = dot2h(wv.y, hq.y, a1);
        a2 = dot2h(wv.z, hq.z, a2);
        a3 = dot2h(wv.w, hq.w, a3);
      }
      zc[tid] = (a0 + a1) + (a2 + a3);
    }
    __syncthreads();
    if (tid < 200) {
      float iv = sigf(zc[tid]);
      float fv = sigf(zc[200 + tid]);
      float gv = tanhf_fast(zc[400 + tid]);
      float ov = sigf(zc[600 + tid]);
      cst = fv * cst + iv * gv;
      float h = ov * tanhf_fast(cst);
      ((u16*)hl2)[tid] = __half_as_ushort(__float2half(h));
      dout[(size_t)t * 1808 + tid] = h;
    }
    __syncthreads();
  }
}

// ---------- launch ----------
extern "C" void kernel_launch(void* const* d_in, const int* in_sizes, int n_in, void* d_out,
                              int out_size, void* d_ws, size_t ws_size, hipStream_t stream) {
  const float* emb = (const float*)d_in[0];
  const float* info = (const float*)d_in[1];
  const int* cspan = (const int*)d_in[2];
  const int* aspan = (const int*)d_in[3];
  const void* amask = d_in[4];
  const void* lmask = d_in[5];
  const int* isrc = (const int*)d_in[6];
  const int* idst = (const int*)d_in[7];
  const int* irel = (const int*)d_in[8];
  const void* imask = d_in[9];
  const int* tsrc = (const int*)d_in[10];
  const int* tdst = (const int*)d_in[11];
  const int* trel = (const int*)d_in[12];
  const void* tmask = d_in[13];
  const float* Wihf = (const float*)d_in[14];
  const float* Whhf = (const float*)d_in[15];
  const float* bfv = (const float*)d_in[16];
  const float* Wihb = (const float*)d_in[17];
  const float* Whhb = (const float*)d_in[18];
  const float* bbv = (const float*)d_in[19];
  const float* Wgat = (const float*)d_in[20];
  const float* al = (const float*)d_in[21];
  const float* ar = (const float*)d_in[22];
  const float* bgat = (const float*)d_in[23];
  const float* Wsem = (const float*)d_in[24];
  const float* bsem = (const float*)d_in[25];
  const float* qsem = (const float*)d_in[26];
  const float* Wpred = (const float*)d_in[27];
  const float* bpred = (const float*)d_in[28];
  const float* Wadu1 = (const float*)d_in[29];
  const float* badu1 = (const float*)d_in[30];
  const float* Wadu2 = (const float*)d_in[31];
  const float* badu2 = (const float*)d_in[32];
  const float* Winn1 = (const float*)d_in[33];
  const float* binn1 = (const float*)d_in[34];
  const float* Winn2 = (const float*)d_in[35];
  const float* binn2 = (const float*)d_in[36];
  const float* Wint1 = (const float*)d_in[37];
  const float* bint1 = (const float*)d_in[38];
  const float* Wint2 = (const float*)d_in[39];
  const float* bint2 = (const float*)d_in[40];
  const float* Wihc = (const float*)d_in[41];
  const float* Whhc = (const float*)d_in[42];
  const float* bc = (const float*)d_in[43];
  float* out = (float*)d_out;
  float* ws = (float*)d_ws;

  const size_t OFF_Z = 0;                                    // 65536*640
  const size_t OFF_HF = OFF_Z + (size_t)65536 * 640;         // 64*1024*80
  const size_t OFF_HB = OFF_HF + (size_t)64 * 1024 * 80;
  const size_t OFF_ZG = OFF_HB + (size_t)64 * 1024 * 80;     // 64*4*32*768
  const size_t OFF_AD = OFF_ZG + (size_t)64 * 4 * 32 * 768;  // 64*32*320
  const size_t OFF_CE = OFF_AD + (size_t)64 * 32 * 320;      // 64*320
  const size_t OFF_WS4 = OFF_CE + 64 * 320;                  // 256
  const size_t OFF_ALP = OFF_WS4 + 256;                      // 3840
  const size_t OFF_ARP = OFF_ALP + 3840;                     // 3840
  const size_t OFF_WO = OFF_ARP + 3840;                      // 64*1608
  const size_t OFF_XC = OFF_WO + (size_t)64 * 1608;          // 64*800
  const size_t OFF_WT = OFF_XC + (size_t)64 * 800;           // 80000 u32
  const size_t TOTAL = OFF_WT + 80000;

  if (n_in < 44 || ws_size < TOTAL * sizeof(float)) {
    k_marker<<<1, 1, 0, stream>>>(out);
    return;
  }

  k_prep<<<960, 256, 0, stream>>>(Wgat, al, ar, ws + OFF_ALP, ws + OFF_ARP);
  k_pack<<<79, 256, 0, stream>>>(Whhc, (uint4*)(ws + OFF_WT));
  dim3 g1(5, 512);  // n-tiles fastest: 5 consecutive blocks reuse one A-panel
  k_gemm_in<<<g1, 256, 0, stream>>>(emb, Wihf, Wihb, bfv, bbv, ws + OFF_Z);
  k_lstm_tok<<<128, 320, 0, stream>>>(ws + OFF_Z, Whhf, Whhb, ws + OFF_HF, ws + OFF_HB);
  k_span<<<64, 256, 0, stream>>>(ws + OFF_HF, ws + OFF_HB, cspan, aspan, amask, ws + OFF_AD,
                                 ws + OFF_CE);
  k_gat<<<256, 256, 0, stream>>>(ws + OFF_AD, ws + OFF_ALP, ws + OFF_ARP, Wgat, bgat, isrc, idst,
                                 irel, imask, tsrc, tdst, trel, tmask, amask, ws + OFF_ZG);
  k_sem<<<256, 256, 0, stream>>>(ws + OFF_ZG, Wsem, bsem, qsem, amask, ws + OFF_WS4);
  k_comment<<<64, 256, 0, stream>>>(ws + OFF_ZG, ws + OFF_WS4, ws + OFF_CE, Wpred, bpred, Wadu1,
                                    badu1, Wadu2, badu2, Winn1, binn1, Winn2, binn2, Wint1, bint1,
                                    Wint2, bint2, info, amask, lmask, isrc, idst, irel, imask,
                                    tsrc, tdst, trel, tmask, ws + OFF_WO, out);
  k_ctx_in<<<100, 256, 0, stream>>>(ws + OFF_WO, Wihc, bc, ws + OFF_XC);
  k_ctx_rec<<<1, 832, 0, stream>>>(ws + OFF_XC, (const uint4*)(ws + OFF_WT), out);
}

// Round 17
// 1575.459 us; speedup vs baseline: 1.1702x; 1.0515x over previous
//
#include <hip/hip_runtime.h>
#include <hip/hip_bf16.h>
#include <hip/hip_fp16.h>
#include <stdint.h>

typedef unsigned int u32;
typedef unsigned short u16;
typedef __attribute__((ext_vector_type(8))) short short8;
typedef __attribute__((ext_vector_type(4))) float f32x4;
typedef _Float16 half2v __attribute__((ext_vector_type(2)));

#if defined(__has_builtin)
#if __has_builtin(__builtin_amdgcn_fdot2)
#define HAVE_FDOT2 1
#endif
#endif

// LDS-only barrier: drains lgkmcnt (LDS ordering) but leaves global loads in
// flight across the barrier (AITER pattern; __syncthreads would vmcnt(0)-drain
// the z prefetch every step, exposing full HBM latency per LSTM step).
#define LDS_BARRIER()                                        \
  do {                                                       \
    asm volatile("s_waitcnt lgkmcnt(0)" ::: "memory");       \
    __builtin_amdgcn_s_barrier();                            \
    asm volatile("" ::: "memory");                           \
  } while (0)

// ---------- helpers ----------
__device__ __forceinline__ float bf2f_u(u32 lo16) { return __uint_as_float(lo16 << 16); }
__device__ __forceinline__ u32 f2bf_bits(float x) {
  u32 u = __float_as_uint(x);
  return (u + 0x7fffu + ((u >> 16) & 1u)) >> 16;
}
__device__ __forceinline__ u32 pk2bf_tr(float x, float y) {  // truncating pack, 2 VALU
  return (__float_as_uint(y) & 0xffff0000u) | (__float_as_uint(x) >> 16);
}
__device__ __forceinline__ u32 pkh(float x, float y) {  // two f16 in a u32
  return (u32)__half_as_ushort(__float2half(x)) |
         ((u32)__half_as_ushort(__float2half(y)) << 16);
}
__device__ __forceinline__ float dot2h(u32 w, u32 h, float acc) {
#ifdef HAVE_FDOT2
  return __builtin_amdgcn_fdot2(__builtin_bit_cast(half2v, w), __builtin_bit_cast(half2v, h),
                                acc, false);
#else
  union { u32 u; __half2 h2; } uw, uh;
  uw.u = w; uh.u = h;
  float2 wf = __half22float2(uw.h2);
  float2 hf = __half22float2(uh.h2);
  return acc + wf.x * hf.x + wf.y * hf.y;
#endif
}
__device__ __forceinline__ float sigf(float x) { return 1.0f / (1.0f + __expf(-x)); }
__device__ __forceinline__ float tanhf_fast(float x) {
  float ax = fabsf(x);
  float e = __expf(-2.0f * ax);
  float t = (1.0f - e) / (1.0f + e);
  return x < 0.0f ? -t : t;
}
__device__ __forceinline__ float eluf(float x) { return x > 0.0f ? x : __expf(x) - 1.0f; }
__device__ __forceinline__ float lreluf(float x) { return x > 0.0f ? x : 0.2f * x; }

__device__ __forceinline__ int maskmode(const void* am) { return (*(const u32*)am) > 0xFFu; }
__device__ __forceinline__ int ldmask(const void* p, int i, int mb) {
  return mb ? (int)((const unsigned char*)p)[i] : ((const int*)p)[i];
}

__global__ void k_marker(float* out) { out[0] = 12345.0f; }

// ---------- K0: precompute W_gat @ a_l / a_r (wave-per-output, coalesced) ----------
__global__ __launch_bounds__(256) void k_prep(const float* __restrict__ Wgat,
                                              const float* __restrict__ al,
                                              const float* __restrict__ ar,
                                              float* __restrict__ alproj,
                                              float* __restrict__ arproj) {
  int w = blockIdx.x * 4 + (threadIdx.x >> 6);
  int lane = threadIdx.x & 63;
  if (w >= 3840) return;
  int mk = w / 320, d = w % 320;
  const float* wrow = Wgat + ((size_t)mk * 320 + d) * 256;
  const float* alp = al + mk * 256;
  const float* arp = ar + mk * 256;
  float sa = 0.f, sb = 0.f;
#pragma unroll
  for (int q = 0; q < 4; ++q) {
    int o = lane + q * 64;
    float wv = wrow[o];
    sa += wv * alp[o];
    sb += wv * arp[o];
  }
#pragma unroll
  for (int off = 32; off; off >>= 1) {
    sa += __shfl_down(sa, off, 64);
    sb += __shfl_down(sb, off, 64);
  }
  if (lane == 0) { alproj[w] = sa; arproj[w] = sb; }
}

// ---------- K0b: Whh_c -> wt4[k4][800] uint4 of f16 pairs ----------
__global__ void k_pack(const float* __restrict__ whhc, uint4* __restrict__ wt4) {
  int idx = blockIdx.x * 256 + threadIdx.x;
  if (idx >= 20000) return;
  int k4 = idx / 800, r = idx % 800;
  const float* p = whhc + r * 200 + k4 * 8;
  wt4[idx] = (uint4){pkh(p[0], p[1]), pkh(p[2], p[3]), pkh(p[4], p[5]), pkh(p[6], p[7])};
}

// ---------- K1: input GEMM (MFMA bf16), trunc pack-in-loop, plain Z[m][640] ----------
__global__ __launch_bounds__(256) void k_gemm_in(
    const float* __restrict__ emb, const float* __restrict__ Wf, const float* __restrict__ Wb,
    const float* __restrict__ biasf, const float* __restrict__ biasb, float* __restrict__ Z) {
  __shared__ u16 Albs[128 * 40];
  __shared__ u16 Blbs[128 * 40];
  __shared__ float bias_l[128];
  const int tid = threadIdx.x;
  const int n0 = blockIdx.x * 128;
  const int m0 = blockIdx.y * 128;

  if (tid < 128) {
    int ng = n0 + tid;
    bias_l[tid] = (ng < 320) ? biasf[ng] : biasb[ng - 320];
  }
  const int srow = tid >> 1, shalf = tid & 1;
  const float* asrc = emb + (size_t)(m0 + srow) * 768 + shalf * 16;
  const int ngb = n0 + srow;
  const float* bsrc =
      ((ngb < 320) ? (Wf + (size_t)ngb * 768) : (Wb + (size_t)(ngb - 320) * 768)) + shalf * 16;
  u32* aw = (u32*)&Albs[srow * 40 + shalf * 16];
  u32* bw = (u32*)&Blbs[srow * 40 + shalf * 16];

  const int lane = tid & 63;
  const int lr = lane & 15, sub = lane >> 4;
  const int wv = tid >> 6, wm = wv >> 1, wn = wv & 1;
  const u16* abase = &Albs[(wm * 64 + lr) * 40 + sub * 8];
  const u16* bbase = &Blbs[(wn * 64 + lr) * 40 + sub * 8];

  f32x4 acc[4][4];
#pragma unroll
  for (int i = 0; i < 4; ++i)
#pragma unroll
    for (int j = 0; j < 4; ++j) acc[i][j] = (f32x4)(0.f);

  float4 a0, a1, a2, a3, b0, b1, b2, b3;
  u32 pra[8], prb[8];
  a0 = *(const float4*)(asrc + 0); a1 = *(const float4*)(asrc + 4);
  a2 = *(const float4*)(asrc + 8); a3 = *(const float4*)(asrc + 12);
  b0 = *(const float4*)(bsrc + 0); b1 = *(const float4*)(bsrc + 4);
  b2 = *(const float4*)(bsrc + 8); b3 = *(const float4*)(bsrc + 12);
  pra[0] = pk2bf_tr(a0.x, a0.y); pra[1] = pk2bf_tr(a0.z, a0.w);
  pra[2] = pk2bf_tr(a1.x, a1.y); pra[3] = pk2bf_tr(a1.z, a1.w);
  pra[4] = pk2bf_tr(a2.x, a2.y); pra[5] = pk2bf_tr(a2.z, a2.w);
  pra[6] = pk2bf_tr(a3.x, a3.y); pra[7] = pk2bf_tr(a3.z, a3.w);
  prb[0] = pk2bf_tr(b0.x, b0.y); prb[1] = pk2bf_tr(b0.z, b0.w);
  prb[2] = pk2bf_tr(b1.x, b1.y); prb[3] = pk2bf_tr(b1.z, b1.w);
  prb[4] = pk2bf_tr(b2.x, b2.y); prb[5] = pk2bf_tr(b2.z, b2.w);
  prb[6] = pk2bf_tr(b3.x, b3.y); prb[7] = pk2bf_tr(b3.z, b3.w);

  for (int it = 0; it < 24; ++it) {
    __syncthreads();
#pragma unroll
    for (int q = 0; q < 8; ++q) { aw[q] = pra[q]; bw[q] = prb[q]; }
    __syncthreads();
    const bool more = (it + 1 < 24);
    if (more) {
      const int k0 = (it + 1) * 32;
      a0 = *(const float4*)(asrc + k0); a1 = *(const float4*)(asrc + k0 + 4);
      a2 = *(const float4*)(asrc + k0 + 8); a3 = *(const float4*)(asrc + k0 + 12);
      b0 = *(const float4*)(bsrc + k0); b1 = *(const float4*)(bsrc + k0 + 4);
      b2 = *(const float4*)(bsrc + k0 + 8); b3 = *(const float4*)(bsrc + k0 + 12);
    }
    short8 bfr[4];
#pragma unroll
    for (int nf = 0; nf < 4; ++nf) bfr[nf] = *(const short8*)(bbase + nf * 640);
#pragma unroll
    for (int mf = 0; mf < 4; ++mf) {
      short8 af = *(const short8*)(abase + mf * 640);
#pragma unroll
      for (int nf = 0; nf < 4; ++nf)
        acc[mf][nf] = __builtin_amdgcn_mfma_f32_16x16x32_bf16(af, bfr[nf], acc[mf][nf], 0, 0, 0);
    }
    if (more) {
      pra[0] = pk2bf_tr(a0.x, a0.y); pra[1] = pk2bf_tr(a0.z, a0.w);
      pra[2] = pk2bf_tr(a1.x, a1.y); pra[3] = pk2bf_tr(a1.z, a1.w);
      pra[4] = pk2bf_tr(a2.x, a2.y); pra[5] = pk2bf_tr(a2.z, a2.w);
      pra[6] = pk2bf_tr(a3.x, a3.y); pra[7] = pk2bf_tr(a3.z, a3.w);
      prb[0] = pk2bf_tr(b0.x, b0.y); prb[1] = pk2bf_tr(b0.z, b0.w);
      prb[2] = pk2bf_tr(b1.x, b1.y); prb[3] = pk2bf_tr(b1.z, b1.w);
      prb[4] = pk2bf_tr(b2.x, b2.y); prb[5] = pk2bf_tr(b2.z, b2.w);
      prb[6] = pk2bf_tr(b3.x, b3.y); prb[7] = pk2bf_tr(b3.z, b3.w);
    }
  }
#pragma unroll
  for (int mf = 0; mf < 4; ++mf) {
#pragma unroll
    for (int nf = 0; nf < 4; ++nf) {
      int col = wn * 64 + nf * 16 + lr;
      float bias = bias_l[col];
      size_t mrow = (size_t)m0 + wm * 64 + mf * 16 + sub * 4;
#pragma unroll
      for (int j = 0; j < 4; ++j)
        Z[(mrow + j) * 640 + n0 + col] = acc[mf][nf][j] + bias;
    }
  }
}

// ---------- K2: token LSTM (round-16 + LDS-only barriers in the step loop).
// Activation hoisted to producer (round-16). In-loop barriers drain ONLY lgkmcnt:
// the z prefetch (global load for t+2) stays in flight across barriers instead of
// being vmcnt(0)-drained each step by __syncthreads.
__global__ __launch_bounds__(320, 1) void k_lstm_tok(const float* __restrict__ Z,
                                                     const float* __restrict__ Whhf,
                                                     const float* __restrict__ Whhb,
                                                     float* __restrict__ hf,
                                                     float* __restrict__ hb) {
  __shared__ uint2 wq[20 * 320];
  __shared__ alignas(16) u32 hpk[40];
  __shared__ float zbuf[320];
  const int tid = threadIdx.x;
  const int c = blockIdx.x >> 1;
  const int dir = blockIdx.x & 1;
  const float* Whh = dir ? Whhb : Whhf;
  float* hout = dir ? hb : hf;

  for (int idx = tid; idx < 20 * 320; idx += 320) {
    int k4 = idx / 320, r = idx % 320;
    const float* p = Whh + (size_t)r * 80 + k4 * 4;
    wq[idx] = (uint2){pkh(p[0], p[1]), pkh(p[2], p[3])};
  }
  if (tid < 40) hpk[tid] = 0;
  __syncthreads();

  const int j = tid;
  const bool isG = (j >= 160) && (j < 240);  // g-gate rows tanh; others sigmoid
  const uint2* wcol = wq + j;
  uint2 wv0 = wcol[0], wv1 = wcol[320], wv2 = wcol[640], wv3 = wcol[960];
  uint2 wv4 = wcol[1280], wv5 = wcol[1600], wv6 = wcol[1920], wv7 = wcol[2240];
  uint2 wv8 = wcol[2560], wv9 = wcol[2880], wv10 = wcol[3200], wv11 = wcol[3520];
  uint2 wv12 = wcol[3840], wv13 = wcol[4160], wv14 = wcol[4480], wv15 = wcol[4800];
  uint2 wv16 = wcol[5120], wv17 = wcol[5440], wv18 = wcol[5760], wv19 = wcol[6080];

  const int sgn = dir ? -1 : 1;
  const int t0 = dir ? 1023 : 0;
  const float* zb = Z + (size_t)c * 1024 * 640 + dir * 320 + j;
  float zc = zb[(size_t)t0 * 640];
  float zn = zb[(size_t)(t0 + sgn) * 640];
  float cst = 0.f;

  for (int t = 0; t < 1024; ++t) {
    const int tt = t0 + sgn * t;
    float zp = 0.f;
    if (t + 2 < 1024) zp = zb[(size_t)(t0 + sgn * (t + 2)) * 640];
    float a0 = zc, a1 = 0.f, a2 = 0.f, a3 = 0.f;
    {
      uint4 h0 = *(const uint4*)&hpk[0];
      a0 = dot2h(wv0.x, h0.x, a0); a1 = dot2h(wv0.y, h0.y, a1);
      a2 = dot2h(wv1.x, h0.z, a2); a3 = dot2h(wv1.y, h0.w, a3);
      uint4 h1 = *(const uint4*)&hpk[4];
      a0 = dot2h(wv2.x, h1.x, a0); a1 = dot2h(wv2.y, h1.y, a1);
      a2 = dot2h(wv3.x, h1.z, a2); a3 = dot2h(wv3.y, h1.w, a3);
      uint4 h2 = *(const uint4*)&hpk[8];
      a0 = dot2h(wv4.x, h2.x, a0); a1 = dot2h(wv4.y, h2.y, a1);
      a2 = dot2h(wv5.x, h2.z, a2); a3 = dot2h(wv5.y, h2.w, a3);
      uint4 h3 = *(const uint4*)&hpk[12];
      a0 = dot2h(wv6.x, h3.x, a0); a1 = dot2h(wv6.y, h3.y, a1);
      a2 = dot2h(wv7.x, h3.z, a2); a3 = dot2h(wv7.y, h3.w, a3);
      uint4 h4 = *(const uint4*)&hpk[16];
      a0 = dot2h(wv8.x, h4.x, a0); a1 = dot2h(wv8.y, h4.y, a1);
      a2 = dot2h(wv9.x, h4.z, a2); a3 = dot2h(wv9.y, h4.w, a3);
      uint4 h5 = *(const uint4*)&hpk[20];
      a0 = dot2h(wv10.x, h5.x, a0); a1 = dot2h(wv10.y, h5.y, a1);
      a2 = dot2h(wv11.x, h5.z, a2); a3 = dot2h(wv11.y, h5.w, a3);
      uint4 h6 = *(const uint4*)&hpk[24];
      a0 = dot2h(wv12.x, h6.x, a0); a1 = dot2h(wv12.y, h6.y, a1);
      a2 = dot2h(wv13.x, h6.z, a2); a3 = dot2h(wv13.y, h6.w, a3);
      uint4 h7 = *(const uint4*)&hpk[28];
      a0 = dot2h(wv14.x, h7.x, a0); a1 = dot2h(wv14.y, h7.y, a1);
      a2 = dot2h(wv15.x, h7.z, a2); a3 = dot2h(wv15.y, h7.w, a3);
      uint4 h8 = *(const uint4*)&hpk[32];
      a0 = dot2h(wv16.x, h8.x, a0); a1 = dot2h(wv16.y, h8.y, a1);
      a2 = dot2h(wv17.x, h8.z, a2); a3 = dot2h(wv17.y, h8.w, a3);
      uint4 h9 = *(const uint4*)&hpk[36];
      a0 = dot2h(wv18.x, h9.x, a0); a1 = dot2h(wv18.y, h9.y, a1);
      a2 = dot2h(wv19.x, h9.z, a2); a3 = dot2h(wv19.y, h9.w, a3);
    }
    float zr = (a0 + a1) + (a2 + a3);
    zbuf[j] = isG ? tanhf_fast(zr) : sigf(zr);  // activation hoisted to producer
    LDS_BARRIER();
    if (j < 80) {
      float iv = zbuf[j];
      float fv = zbuf[80 + j];
      float gv = zbuf[160 + j];
      float ov = zbuf[240 + j];
      cst = fv * cst + iv * gv;
      float h = ov * tanhf_fast(cst);
      ((u16*)hpk)[j] = (u16)__half_as_ushort(__float2half(h));
      hout[((size_t)c * 1024 + tt) * 80 + j] = h;
    }
    zc = zn; zn = zp;
    LDS_BARRIER();
  }
}

// ---------- span representation ----------
__device__ __forceinline__ float span_val(const float* __restrict__ hf,
                                          const float* __restrict__ hb, int c, int i, int j,
                                          int d) {
  size_t base = (size_t)c * 1024 * 80;
  if (d < 80) return hf[base + (size_t)j * 80 + d] - hf[base + (size_t)(i - 1) * 80 + d];
  if (d < 160) return hb[base + (size_t)i * 80 + (d - 80)] - hb[base + (size_t)(j + 1) * 80 + (d - 80)];
  if (d < 240) return hf[base + (size_t)(i - 1) * 80 + (d - 160)];
  return hb[base + (size_t)(j + 1) * 80 + (d - 240)];
}

__global__ __launch_bounds__(256) void k_span(const float* __restrict__ hf,
                                              const float* __restrict__ hb,
                                              const int* __restrict__ cspan,
                                              const int* __restrict__ aspan,
                                              const void* __restrict__ amask,
                                              float* __restrict__ adus, float* __restrict__ cembo) {
  const int c = blockIdx.x, tid = threadIdx.x;
  const int mb = maskmode(amask);
  int ci = cspan[c * 2], cj = cspan[c * 2 + 1];
  for (int d = tid; d < 320; d += 256) cembo[c * 320 + d] = span_val(hf, hb, c, ci, cj, d);
  for (int idx = tid; idx < 32 * 320; idx += 256) {
    int a = idx / 320, d = idx % 320;
    float v = 0.f;
    if (ldmask(amask, c * 32 + a, mb)) {
      int ai = aspan[(c * 32 + a) * 2], aj = aspan[(c * 32 + a) * 2 + 1];
      v = span_val(hf, hb, c, ai, aj, d);
    }
    adus[(size_t)c * 10240 + idx] = v;
  }
}

// ---------- K3a: GAT per (comment, metapath); Wst tile prefetch ----------
__global__ __launch_bounds__(256) void k_gat(
    const float* __restrict__ adus_ws, const float* __restrict__ alproj,
    const float* __restrict__ arproj, const float* __restrict__ Wgat,
    const float* __restrict__ bgat, const int* __restrict__ isrc, const int* __restrict__ idst,
    const int* __restrict__ irel, const void* __restrict__ imask, const int* __restrict__ tsrc,
    const int* __restrict__ tdst, const int* __restrict__ trel, const void* __restrict__ tmask,
    const void* __restrict__ amdet, float* __restrict__ zgat) {
  __shared__ float adus_l[32][321];
  __shared__ float Wst[16][64];
  __shared__ float hp_t[32][66];
  __shared__ float sl_l[96], sr_l[96];
  __shared__ float e_l[144], alpha_l[144], mx_l[96], den_l[96];
  __shared__ int src_l[48], dst_l[48], valid_l[48];
  const int c = blockIdx.x >> 2, m = blockIdx.x & 3;
  const int tid = threadIdx.x;
  const int mb = maskmode(amdet);

  if (tid < 48) {
    int e = tid, s, d, r, mk;
    if (m < 2) {
      s = isrc[c * 48 + e]; d = idst[c * 48 + e]; r = irel[c * 48 + e];
      mk = ldmask(imask, c * 48 + e, mb);
    } else {
      s = tdst[c * 48 + e]; d = tsrc[c * 48 + e]; r = trel[c * 48 + e];
      mk = ldmask(tmask, c * 48 + e, mb);
    }
    src_l[e] = s; dst_l[e] = d; valid_l[e] = (mk != 0) && (r == (m & 1));
  }
  for (int idx = tid; idx < 32 * 320; idx += 256)
    adus_l[idx / 320][idx % 320] = adus_ws[(size_t)c * 10240 + idx];
  __syncthreads();

  if (tid < 96) {
    int a = tid & 31, k = tid >> 5;
    const float* alp = alproj + (m * 3 + k) * 320;
    const float* arp = arproj + (m * 3 + k) * 320;
    float sa = 0.f, sb = 0.f;
    for (int d = 0; d < 320; ++d) {
      float v = adus_l[a][d];
      sa += v * alp[d];
      sb += v * arp[d];
    }
    sl_l[a * 3 + k] = sa;
    sr_l[a * 3 + k] = sb;
  }
  __syncthreads();
  if (tid < 144) {
    int e = tid % 48, k = tid / 48;
    float v = -1e30f;
    if (valid_l[e]) v = lreluf(sl_l[src_l[e] * 3 + k] + sr_l[dst_l[e] * 3 + k]);
    e_l[e * 3 + k] = v;
  }
  __syncthreads();
  if (tid < 96) {
    int a = tid & 31, k = tid >> 5;
    float mx = -1e30f;
    for (int e = 0; e < 48; ++e)
      if (valid_l[e] && dst_l[e] == a) mx = fmaxf(mx, e_l[e * 3 + k]);
    float den = 0.f;
    for (int e = 0; e < 48; ++e)
      if (valid_l[e] && dst_l[e] == a) den += __expf(e_l[e * 3 + k] - mx);
    mx_l[a * 3 + k] = mx;
    den_l[a * 3 + k] = den;
  }
  __syncthreads();
  if (tid < 144) {
    int e = tid % 48, k = tid / 48;
    float v = 0.f;
    if (valid_l[e]) {
      int d = dst_l[e];
      v = __expf(e_l[e * 3 + k] - mx_l[d * 3 + k]) / fmaxf(den_l[d * 3 + k], 1e-9f);
    }
    alpha_l[e * 3 + k] = v;
  }
  __syncthreads();

  const int ag = tid >> 3, og = tid & 7;
  const int dd_ = tid >> 4, oq_ = (tid & 15) * 4;
  for (int k = 0; k < 3; ++k) {
    for (int ot = 0; ot < 4; ++ot) {
      float acc[8];
#pragma unroll
      for (int i = 0; i < 8; ++i) acc[i] = 0.f;
      float4 pref = *(const float4*)(Wgat + ((size_t)((m * 3 + k) * 320 + dd_)) * 256 + ot * 64 + oq_);
      for (int dt = 0; dt < 320; dt += 16) {
        Wst[dd_][oq_ + 0] = pref.x;
        Wst[dd_][oq_ + 1] = pref.y;
        Wst[dd_][oq_ + 2] = pref.z;
        Wst[dd_][oq_ + 3] = pref.w;
        __syncthreads();
        if (dt + 16 < 320)
          pref = *(const float4*)(Wgat +
                                  ((size_t)((m * 3 + k) * 320 + dt + 16 + dd_)) * 256 + ot * 64 + oq_);
#pragma unroll
        for (int dd = 0; dd < 16; ++dd) {
          float av = adus_l[ag][dt + dd];
          const float4 w0 = *(const float4*)(&Wst[dd][og * 8]);
          const float4 w1 = *(const float4*)(&Wst[dd][og * 8 + 4]);
          acc[0] += av * w0.x; acc[1] += av * w0.y; acc[2] += av * w0.z; acc[3] += av * w0.w;
          acc[4] += av * w1.x; acc[5] += av * w1.y; acc[6] += av * w1.z; acc[7] += av * w1.w;
        }
        __syncthreads();
      }
#pragma unroll
      for (int i = 0; i < 8; ++i) hp_t[ag][og * 8 + i] = acc[i];
      __syncthreads();
      float oacc[8];
#pragma unroll
      for (int i = 0; i < 8; ++i) oacc[i] = 0.f;
      for (int e = 0; e < 48; ++e) {
        if (valid_l[e] && dst_l[e] == ag) {
          float alv = alpha_l[e * 3 + k];
          int s = src_l[e];
#pragma unroll
          for (int i = 0; i < 8; ++i) oacc[i] += alv * hp_t[s][og * 8 + i];
        }
      }
#pragma unroll
      for (int i = 0; i < 8; ++i) {
        int o = ot * 64 + og * 8 + i;
        float v = eluf(oacc[i] + bgat[(m * 3 + k) * 256 + o]);
        zgat[((size_t)(c * 4 + m) * 32 + ag) * 768 + k * 256 + o] = v;
      }
      __syncthreads();
    }
  }
}

// ---------- K3w: semantic attention ----------
__global__ __launch_bounds__(256) void k_sem(const float* __restrict__ zgat,
                                             const float* __restrict__ Wsem,
                                             const float* __restrict__ bsem,
                                             const float* __restrict__ qsem,
                                             const void* __restrict__ amask,
                                             float* __restrict__ wsem) {
  __shared__ float Wst[64][128];
  __shared__ float zl[32][64];
  __shared__ float wred[256];
  __shared__ float war[32];
  const int c = blockIdx.x >> 2, m = blockIdx.x & 3;
  const int tid = threadIdx.x;
  const int mb = maskmode(amask);
  const int a = tid >> 3, hg = tid & 7;
  float acc[16];
#pragma unroll
  for (int i = 0; i < 16; ++i) acc[i] = 0.f;
  const float* zbase = zgat + (size_t)(c * 4 + m) * 32 * 768;
  for (int jt = 0; jt < 768; jt += 64) {
    for (int l = 0; l < 8; ++l) {
      int f4 = l * 256 + tid;
      int row = f4 >> 5, c4 = (f4 & 31) * 4;
      *(float4*)&Wst[row][c4] = *(const float4*)(Wsem + (size_t)(jt + row) * 128 + c4);
    }
    for (int l = 0; l < 2; ++l) {
      int f4 = l * 256 + tid;
      int row = f4 >> 4, c4 = (f4 & 15) * 4;
      *(float4*)&zl[row][c4] = *(const float4*)(zbase + (size_t)row * 768 + jt + c4);
    }
    __syncthreads();
    for (int j = 0; j < 64; ++j) {
      float zv = zl[a][j];
      const float* wp = &Wst[j][hg * 16];
#pragma unroll
      for (int i = 0; i < 16; ++i) acc[i] += zv * wp[i];
    }
    __syncthreads();
  }
  float wp_ = 0.f;
#pragma unroll
  for (int i = 0; i < 16; ++i) {
    int h = hg * 16 + i;
    wp_ += tanhf_fast(acc[i] + bsem[h]) * qsem[h];
  }
  wred[tid] = wp_;
  __syncthreads();
  if (tid < 32) {
    float s = 0.f;
    for (int q = 0; q < 8; ++q) s += wred[tid * 8 + q];
    war[tid] = s;
  }
  __syncthreads();
  if (tid == 0) {
    float s = 0.f;
    int cnt = 0;
    for (int aa = 0; aa < 32; ++aa)
      if (ldmask(amask, c * 32 + aa, mb)) { s += war[aa]; cnt++; }
    wsem[c * 4 + m] = s / (float)(cnt > 1 ? cnt : 1);
  }
}

// ---------- K3b: per-comment assembly. Weights staged in LDS (wbuf 53KB). ----------
__global__ __launch_bounds__(256) void k_comment(
    const float* __restrict__ zgat, const float* __restrict__ wsem,
    const float* __restrict__ cemb_ws, const float* __restrict__ Wpred,
    const float* __restrict__ bpred, const float* __restrict__ Wadu1,
    const float* __restrict__ badu1, const float* __restrict__ Wadu2,
    const float* __restrict__ badu2, const float* __restrict__ Winn1,
    const float* __restrict__ binn1, const float* __restrict__ Winn2,
    const float* __restrict__ binn2, const float* __restrict__ Wint1,
    const float* __restrict__ bint1, const float* __restrict__ Wint2,
    const float* __restrict__ bint2, const float* __restrict__ info,
    const void* __restrict__ amask, const void* __restrict__ lmask,
    const int* __restrict__ isrc, const int* __restrict__ idst,
    const int* __restrict__ irel, const void* __restrict__ imask, const int* __restrict__ tsrc,
    const int* __restrict__ tdst, const int* __restrict__ trel, const void* __restrict__ tmask,
    float* __restrict__ woctx, float* __restrict__ dout) {
  __shared__ float zf[32][133];
  __shared__ float ae[32][257];
  __shared__ float wbuf[13344];
  __shared__ float cemb_l[320];
  __shared__ float beta_l[4];
  __shared__ float pred_l[48][16];
  __shared__ float sE[48], alE[48];
  __shared__ int seL[48], deL[48], relL[48], mskL[48];
  __shared__ float wredA[256];
  __shared__ float sA[32], alA[32];
  __shared__ int mskA[32];
  const int c = blockIdx.x, tid = threadIdx.x;
  const int mb = maskmode(amask);

  if (tid == 0) {
    float w0 = wsem[c * 4], w1 = wsem[c * 4 + 1], w2 = wsem[c * 4 + 2], w3 = wsem[c * 4 + 3];
    float mx = fmaxf(fmaxf(w0, w1), fmaxf(w2, w3));
    float e0 = __expf(w0 - mx), e1 = __expf(w1 - mx), e2 = __expf(w2 - mx), e3 = __expf(w3 - mx);
    float s = e0 + e1 + e2 + e3;
    beta_l[0] = e0 / s; beta_l[1] = e1 / s; beta_l[2] = e2 / s; beta_l[3] = e3 / s;
  }
  for (int d = tid; d < 320; d += 256) cemb_l[d] = cemb_ws[c * 320 + d];
  __syncthreads();

  const int ag = tid >> 5;
  const int og = tid & 31;
  float acc[4][8];
#pragma unroll
  for (int i = 0; i < 4; ++i)
#pragma unroll
    for (int j = 0; j < 8; ++j) acc[i][j] = 0.f;
  const float b0 = beta_l[0], b1 = beta_l[1], b2 = beta_l[2], b3 = beta_l[3];
  const float* zc0 = zgat + (size_t)(c * 4 + 0) * 32 * 768;
  const float* zc1 = zgat + (size_t)(c * 4 + 1) * 32 * 768;
  const float* zc2 = zgat + (size_t)(c * 4 + 2) * 32 * 768;
  const float* zc3 = zgat + (size_t)(c * 4 + 3) * 32 * 768;
  for (int jt = 0; jt < 768; jt += 128) {
    for (int l = 0; l < 16; ++l) {
      int idx = l * 256 + tid;
      int a = idx >> 7, j = idx & 127;
      size_t off = (size_t)a * 768 + jt + j;
      zf[a][j] = b0 * zc0[off] + b1 * zc1[off] + b2 * zc2[off] + b3 * zc3[off];
    }
    __syncthreads();
    const float* wp0 = Wpred + (size_t)jt * 256 + og * 8;
    float4 w0v = *(const float4*)wp0;
    float4 w1v = *(const float4*)(wp0 + 4);
    for (int j = 0; j < 128; ++j) {
      float4 n0v, n1v;
      if (j + 1 < 128) {
        const float* wp = Wpred + (size_t)(jt + j + 1) * 256 + og * 8;
        n0v = *(const float4*)wp;
        n1v = *(const float4*)(wp + 4);
      }
      float w8[8] = {w0v.x, w0v.y, w0v.z, w0v.w, w1v.x, w1v.y, w1v.z, w1v.w};
      float z0 = zf[ag * 4 + 0][j], z1 = zf[ag * 4 + 1][j];
      float z2 = zf[ag * 4 + 2][j], z3 = zf[ag * 4 + 3][j];
#pragma unroll
      for (int jj = 0; jj < 8; ++jj) {
        acc[0][jj] += z0 * w8[jj];
        acc[1][jj] += z1 * w8[jj];
        acc[2][jj] += z2 * w8[jj];
        acc[3][jj] += z3 * w8[jj];
      }
      if (j + 1 < 128) { w0v = n0v; w1v = n1v; }
    }
    __syncthreads();
  }
#pragma unroll
  for (int i = 0; i < 4; ++i)
#pragma unroll
    for (int jj = 0; jj < 8; ++jj)
      ae[ag * 4 + i][og * 8 + jj] = acc[i][jj] + bpred[og * 8 + jj];
  for (int idx = tid; idx < 9216; idx += 256) wbuf[idx] = Wadu1[idx];
  __syncthreads();

  {
    const int a = tid >> 3, hg = tid & 7;
    float sacc = 0.f;
    for (int hh = 0; hh < 2; ++hh) {
      int h = hg * 2 + hh;
      float d = badu1[h];
      for (int dd = 0; dd < 320; ++dd) d += cemb_l[dd] * wbuf[dd * 16 + h];
      for (int dd = 0; dd < 256; ++dd) d += ae[a][dd] * wbuf[(320 + dd) * 16 + h];
      sacc += fmaxf(d, 0.f) * Wadu2[h];
    }
    wredA[tid] = sacc;
  }
  __syncthreads();
  if (tid < 32) {
    float s = badu2[0];
    for (int q = 0; q < 8; ++q) s += wredA[tid * 8 + q];
    sA[tid] = s;
    mskA[tid] = (ldmask(amask, c * 32 + tid, mb) != 0) && (ldmask(lmask, c * 32 + tid, mb) != 0);
  }
  __syncthreads();
  if (tid == 0) {
    float mx = -1e30f;
    int any = 0;
    for (int a = 0; a < 32; ++a)
      if (mskA[a]) { any = 1; mx = fmaxf(mx, sA[a]); }
    float s = 0.f;
    for (int a = 0; a < 32; ++a) {
      float v = mskA[a] ? __expf(sA[a] - mx) : 0.f;
      alA[a] = v;
      s += v;
    }
    if (any)
      for (int a = 0; a < 32; ++a) alA[a] /= s;
  }
  __syncthreads();
  {
    int o = tid;
    float v = 0.f;
    for (int a = 0; a < 32; ++a) v += alA[a] * ae[a][o];
    woctx[c * 1608 + o] = v;
    dout[(size_t)c * 1808 + 200 + o] = v;
  }
  __syncthreads();

  for (int pp = 0; pp < 2; ++pp) {
    const float *W1, *b1v, *W2, *b2v;
    const int *seP, *deP, *relP;
    const void* mskP;
    int outoff;
    if (pp == 0) {
      W1 = Winn1; b1v = binn1; W2 = Winn2; b2v = binn2;
      seP = isrc; deP = idst; relP = irel; mskP = imask; outoff = 256;
    } else {
      W1 = Wint1; b1v = bint1; W2 = Wint2; b2v = bint2;
      seP = tdst; deP = tsrc; relP = trel; mskP = tmask; outoff = 770;
    }
    if (tid < 48) {
      seL[tid] = seP[c * 48 + tid];
      deL[tid] = deP[c * 48 + tid];
      relL[tid] = relP[c * 48 + tid];
      mskL[tid] = (ldmask(mskP, c * 48 + tid, mb) != 0);
    }
    for (int idx = tid; idx < 13344; idx += 256) wbuf[idx] = W1[idx];
    __syncthreads();
    for (int u = tid; u < 768; u += 256) {
      int e = u >> 4, h = u & 15;
      int se = seL[e], de = deL[e];
      float rel = (float)relL[e];
      float d = b1v[h];
      for (int dd = 0; dd < 320; ++dd) d += cemb_l[dd] * wbuf[dd * 16 + h];
      for (int dd = 0; dd < 256; ++dd) d += ae[se][dd] * wbuf[(320 + dd) * 16 + h];
      for (int dd = 0; dd < 256; ++dd) d += ae[de][dd] * wbuf[(576 + dd) * 16 + h];
      d += rel * wbuf[832 * 16 + h] + (1.f - rel) * wbuf[833 * 16 + h];
      pred_l[e][h] = fmaxf(d, 0.f) * W2[h];
    }
    __syncthreads();
    if (tid < 48) {
      float s = b2v[0];
      for (int h = 0; h < 16; ++h) s += pred_l[tid][h];
      sE[tid] = s;
    }
    __syncthreads();
    if (tid == 0) {
      float mx = -1e30f;
      int any = 0;
      for (int e = 0; e < 48; ++e)
        if (mskL[e]) { any = 1; mx = fmaxf(mx, sE[e]); }
      float s = 0.f;
      for (int e = 0; e < 48; ++e) {
        float v = mskL[e] ? __expf(sE[e] - mx) : 0.f;
        alE[e] = v;
        s += v;
      }
      if (any)
        for (int e = 0; e < 48; ++e) alE[e] /= s;
    }
    __syncthreads();
    for (int dim = tid; dim < 514; dim += 256) {
      float v = 0.f;
      for (int e = 0; e < 48; ++e) {
        float alv = alE[e];
        float pe;
        if (dim < 256) pe = ae[seL[e]][dim];
        else if (dim < 512) pe = ae[deL[e]][dim - 256];
        else if (dim == 512) pe = (float)relL[e];
        else pe = 1.f - (float)relL[e];
        v += alv * pe;
      }
      woctx[c * 1608 + outoff + dim] = v;
      dout[(size_t)c * 1808 + 200 + outoff + dim] = v;
    }
    __syncthreads();
  }

  if (tid < 4) {
    float v = info[c * 4 + tid];
    woctx[c * 1608 + 1284 + tid] = v;
    dout[(size_t)c * 1808 + 200 + 1284 + tid] = v;
  }
  for (int d = tid; d < 320; d += 256) {
    float v = cemb_l[d];
    woctx[c * 1608 + 1288 + d] = v;
    dout[(size_t)c * 1808 + 200 + 1288 + d] = v;
  }
}

// ---------- K4a: ctx LSTM input projection ----------
__global__ __launch_bounds__(256) void k_ctx_in(const float* __restrict__ woctx,
                                                const float* __restrict__ Wihc,
                                                const float* __restrict__ bc,
                                                float* __restrict__ xc) {
  __shared__ float woc[64][133];
  __shared__ float Wst[8][128];
  const int r0 = blockIdx.x * 8;
  const int tid = threadIdx.x;
  const int t = tid & 63, rg = tid >> 6;
  float a0 = 0.f, a1 = 0.f;
  for (int d0 = 0; d0 < 1608; d0 += 128) {
    int jn = 1608 - d0;
    if (jn > 128) jn = 128;
    for (int l = 0; l < 32; ++l) {
      int idx = l * 256 + tid;
      int tt = idx >> 7, j = idx & 127;
      woc[tt][j] = (j < jn) ? woctx[(size_t)tt * 1608 + d0 + j] : 0.f;
    }
    {
      int rr = tid >> 5, jb = tid & 31;
      for (int q = 0; q < 4; ++q) {
        int jj = jb * 4 + q;
        Wst[rr][jj] = (jj < jn) ? Wihc[(size_t)(r0 + rr) * 1608 + d0 + jj] : 0.f;
      }
    }
    __syncthreads();
    for (int j = 0; j < 128; ++j) {
      float x = woc[t][j];
      a0 += x * Wst[rg * 2 + 0][j];
      a1 += x * Wst[rg * 2 + 1][j];
    }
    __syncthreads();
  }
  int r = r0 + rg * 2;
  xc[t * 800 + r] = a0 + bc[r];
  xc[t * 800 + r + 1] = a1 + bc[r + 1];
}

// ---------- K4b: ctx LSTM recurrence ----------
__global__ __launch_bounds__(832) void k_ctx_rec(const float* __restrict__ xc,
                                                 const uint4* __restrict__ wt4,
                                                 float* __restrict__ dout) {
  __shared__ alignas(16) u32 hl2[100];
  __shared__ float zc[800];
  const int tid = threadIdx.x;
  if (tid < 100) hl2[tid] = 0;
  float cst = 0.f;
  __syncthreads();
  for (int t = 0; t < 64; ++t) {
    if (tid < 800) {
      float a0 = xc[t * 800 + tid], a1 = 0.f, a2 = 0.f, a3 = 0.f;
#pragma unroll 5
      for (int k4 = 0; k4 < 25; ++k4) {
        uint4 wv = wt4[(size_t)k4 * 800 + tid];
        uint4 hq = *(const uint4*)&hl2[k4 * 4];
        a0 = dot2h(wv.x, hq.x, a0);
        a1 = dot2h(wv.y, hq.y, a1);
        a2 = dot2h(wv.z, hq.z, a2);
        a3 = dot2h(wv.w, hq.w, a3);
      }
      zc[tid] = (a0 + a1) + (a2 + a3);
    }
    __syncthreads();
    if (tid < 200) {
      float iv = sigf(zc[tid]);
      float fv = sigf(zc[200 + tid]);
      float gv = tanhf_fast(zc[400 + tid]);
      float ov = sigf(zc[600 + tid]);
      cst = fv * cst + iv * gv;
      float h = ov * tanhf_fast(cst);
      ((u16*)hl2)[tid] = __half_as_ushort(__float2half(h));
      dout[(size_t)t * 1808 + tid] = h;
    }
    __syncthreads();
  }
}

// ---------- launch ----------
extern "C" void kernel_launch(void* const* d_in, const int* in_sizes, int n_in, void* d_out,
                              int out_size, void* d_ws, size_t ws_size, hipStream_t stream) {
  const float* emb = (const float*)d_in[0];
  const float* info = (const float*)d_in[1];
  const int* cspan = (const int*)d_in[2];
  const int* aspan = (const int*)d_in[3];
  const void* amask = d_in[4];
  const void* lmask = d_in[5];
  const int* isrc = (const int*)d_in[6];
  const int* idst = (const int*)d_in[7];
  const int* irel = (const int*)d_in[8];
  const void* imask = d_in[9];
  const int* tsrc = (const int*)d_in[10];
  const int* tdst = (const int*)d_in[11];
  const int* trel = (const int*)d_in[12];
  const void* tmask = d_in[13];
  const float* Wihf = (const float*)d_in[14];
  const float* Whhf = (const float*)d_in[15];
  const float* bfv = (const float*)d_in[16];
  const float* Wihb = (const float*)d_in[17];
  const float* Whhb = (const float*)d_in[18];
  const float* bbv = (const float*)d_in[19];
  const float* Wgat = (const float*)d_in[20];
  const float* al = (const float*)d_in[21];
  const float* ar = (const float*)d_in[22];
  const float* bgat = (const float*)d_in[23];
  const float* Wsem = (const float*)d_in[24];
  const float* bsem = (const float*)d_in[25];
  const float* qsem = (const float*)d_in[26];
  const float* Wpred = (const float*)d_in[27];
  const float* bpred = (const float*)d_in[28];
  const float* Wadu1 = (const float*)d_in[29];
  const float* badu1 = (const float*)d_in[30];
  const float* Wadu2 = (const float*)d_in[31];
  const float* badu2 = (const float*)d_in[32];
  const float* Winn1 = (const float*)d_in[33];
  const float* binn1 = (const float*)d_in[34];
  const float* Winn2 = (const float*)d_in[35];
  const float* binn2 = (const float*)d_in[36];
  const float* Wint1 = (const float*)d_in[37];
  const float* bint1 = (const float*)d_in[38];
  const float* Wint2 = (const float*)d_in[39];
  const float* bint2 = (const float*)d_in[40];
  const float* Wihc = (const float*)d_in[41];
  const float* Whhc = (const float*)d_in[42];
  const float* bc = (const float*)d_in[43];
  float* out = (float*)d_out;
  float* ws = (float*)d_ws;

  const size_t OFF_Z = 0;                                    // 65536*640
  const size_t OFF_HF = OFF_Z + (size_t)65536 * 640;         // 64*1024*80
  const size_t OFF_HB = OFF_HF + (size_t)64 * 1024 * 80;
  const size_t OFF_ZG = OFF_HB + (size_t)64 * 1024 * 80;     // 64*4*32*768
  const size_t OFF_AD = OFF_ZG + (size_t)64 * 4 * 32 * 768;  // 64*32*320
  const size_t OFF_CE = OFF_AD + (size_t)64 * 32 * 320;      // 64*320
  const size_t OFF_WS4 = OFF_CE + 64 * 320;                  // 256
  const size_t OFF_ALP = OFF_WS4 + 256;                      // 3840
  const size_t OFF_ARP = OFF_ALP + 3840;                     // 3840
  const size_t OFF_WO = OFF_ARP + 3840;                      // 64*1608
  const size_t OFF_XC = OFF_WO + (size_t)64 * 1608;          // 64*800
  const size_t OFF_WT = OFF_XC + (size_t)64 * 800;           // 80000 u32
  const size_t TOTAL = OFF_WT + 80000;

  if (n_in < 44 || ws_size < TOTAL * sizeof(float)) {
    k_marker<<<1, 1, 0, stream>>>(out);
    return;
  }

  k_prep<<<960, 256, 0, stream>>>(Wgat, al, ar, ws + OFF_ALP, ws + OFF_ARP);
  k_pack<<<79, 256, 0, stream>>>(Whhc, (uint4*)(ws + OFF_WT));
  dim3 g1(5, 512);  // n-tiles fastest: 5 consecutive blocks reuse one A-panel
  k_gemm_in<<<g1, 256, 0, stream>>>(emb, Wihf, Wihb, bfv, bbv, ws + OFF_Z);
  k_lstm_tok<<<128, 320, 0, stream>>>(ws + OFF_Z, Whhf, Whhb, ws + OFF_HF, ws + OFF_HB);
  k_span<<<64, 256, 0, stream>>>(ws + OFF_HF, ws + OFF_HB, cspan, aspan, amask, ws + OFF_AD,
                                 ws + OFF_CE);
  k_gat<<<256, 256, 0, stream>>>(ws + OFF_AD, ws + OFF_ALP, ws + OFF_ARP, Wgat, bgat, isrc, idst,
                                 irel, imask, tsrc, tdst, trel, tmask, amask, ws + OFF_ZG);
  k_sem<<<256, 256, 0, stream>>>(ws + OFF_ZG, Wsem, bsem, qsem, amask, ws + OFF_WS4);
  k_comment<<<64, 256, 0, stream>>>(ws + OFF_ZG, ws + OFF_WS4, ws + OFF_CE, Wpred, bpred, Wadu1,
                                    badu1, Wadu2, badu2, Winn1, binn1, Winn2, binn2, Wint1, bint1,
                                    Wint2, bint2, info, amask, lmask, isrc, idst, irel, imask,
                                    tsrc, tdst, trel, tmask, ws + OFF_WO, out);
  k_ctx_in<<<100, 256, 0, stream>>>(ws + OFF_WO, Wihc, bc, ws + OFF_XC);
  k_ctx_rec<<<1, 832, 0, stream>>>(ws + OFF_XC, (const uint4*)(ws + OFF_WT), out);
}